// Round 13
// baseline (4988.346 us; speedup 1.0000x reference)
//
#include <hip/hip_runtime.h>
#include <math.h>

#define BSZ 1024
#define SLEN 32
#define TLEN 32
#define EDIM 128
#define HLD 266    // u16 row stride (odd dwords -> conflict-free col reads)
#define HFLD 260   // f32 row stride
#define CTXLD 522  // u16 row stride
#define HWLD 260   // f32 row stride

typedef unsigned short u16;
typedef __attribute__((ext_vector_type(8))) short bf16x8;
typedef __attribute__((ext_vector_type(4))) float f32x4;

__device__ __forceinline__ float sgm(float x) { return 1.0f / (1.0f + __expf(-x)); }
__device__ __forceinline__ float tanh_fast(float x) {
  float e = __expf(-2.0f * fabsf(x));
  float t = (1.0f - e) / (1.0f + e);
  return copysignf(t, x);
}
__device__ __forceinline__ u16 f2b(float f) {
  union { float f; unsigned u; } v; v.f = f;
  unsigned r = v.u + 0x7fffu + ((v.u >> 16) & 1u);
  return (u16)(r >> 16);
}
__device__ __forceinline__ float b2f(u16 h) {
  union { unsigned u; float f; } v; v.u = ((unsigned)h) << 16; return v.f;
}

typedef __attribute__((address_space(1))) const void gv_t;
typedef __attribute__((address_space(3))) void lv_t;
__device__ __forceinline__ void gload16(const void* g, void* l) {
  __builtin_amdgcn_global_load_lds((gv_t*)g, (lv_t*)l, 16, 0, 0);
}

// ---------------- gi tables -------------------------------------------------------
__global__ __launch_bounds__(256) void k_gi_table(const float* __restrict__ emb,
                                                  const float* __restrict__ Wih, int ldw,
                                                  const float* __restrict__ bih,
                                                  float* __restrict__ tab) {
  int v = blockIdx.x;
  int g = blockIdx.y * 256 + threadIdx.x;
  __shared__ float e[EDIM];
  if (threadIdx.x < EDIM) e[threadIdx.x] = emb[v * EDIM + threadIdx.x];
  __syncthreads();
  const float4* w4 = (const float4*)(Wih + (size_t)g * ldw);
  float acc = 0.f;
#pragma unroll
  for (int j = 0; j < EDIM / 4; ++j) {
    float4 w = w4[j];
    acc += w.x * e[4 * j] + w.y * e[4 * j + 1] + w.z * e[4 * j + 2] + w.w * e[4 * j + 3];
  }
  tab[(size_t)v * 768 + g] = acc + bih[g];
}

// ---------------- fp32 -> bf16 weight pack ---------------------------------------
__global__ __launch_bounds__(256) void k_pack(u16* __restrict__ dst,
                                              const float* __restrict__ src, int ld,
                                              int off, int n) {
  int r = blockIdx.x;
  for (int c = threadIdx.x; c < n; c += 256)
    dst[(size_t)r * n + c] = f2b(src[(size_t)r * ld + off + c]);
}

// ---------------- bf16 MFMA GEMM 128x64: out = A.B^T + bias ----------------------
template <bool B16OUT>
__global__ __launch_bounds__(256) void k_bgemm(const u16* __restrict__ A, int lda,
                                               const u16* __restrict__ B, int ldb,
                                               const float* __restrict__ bias,
                                               void* __restrict__ outv, int ldo, int K) {
  __shared__ u16 sA[128 * 64];
  __shared__ u16 sB[64 * 64];
  int m0 = blockIdx.x * 128, n0 = blockIdx.y * 64;
  int tid = threadIdx.x, w = tid >> 6, l = tid & 63;
  int wr = w >> 1, wc = w & 1;
  f32x4 acc[4][2] = {};
  for (int k0 = 0; k0 < K; k0 += 64) {
    __syncthreads();
#pragma unroll
    for (int i = 0; i < 4; ++i) {
      int chunk = i * 4 + w;
      int d = chunk * 1024 + l * 16;
      int lg = d ^ (((d >> 7) & 7) << 4);
      int row = lg >> 7, kb = lg & 127;
      gload16((const char*)(A + (size_t)(m0 + row) * lda + k0) + kb, (char*)sA + chunk * 1024);
    }
#pragma unroll
    for (int i = 0; i < 2; ++i) {
      int chunk = i * 4 + w;
      int d = chunk * 1024 + l * 16;
      int lg = d ^ (((d >> 7) & 7) << 4);
      int row = lg >> 7, kb = lg & 127;
      gload16((const char*)(B + (size_t)(n0 + row) * ldb + k0) + kb, (char*)sB + chunk * 1024);
    }
    __syncthreads();
#pragma unroll
    for (int kk = 0; kk < 2; ++kk) {
      bf16x8 av[4], bv[2];
#pragma unroll
      for (int fm = 0; fm < 4; ++fm) {
        int row = wr * 64 + fm * 16 + (l & 15);
        int addr = (row * 128 + kk * 64 + (l >> 4) * 16) ^ ((row & 7) << 4);
        av[fm] = *(const bf16x8*)((const char*)sA + addr);
      }
#pragma unroll
      for (int fn = 0; fn < 2; ++fn) {
        int row = wc * 32 + fn * 16 + (l & 15);
        int addr = (row * 128 + kk * 64 + (l >> 4) * 16) ^ ((row & 7) << 4);
        bv[fn] = *(const bf16x8*)((const char*)sB + addr);
      }
#pragma unroll
      for (int fm = 0; fm < 4; ++fm)
#pragma unroll
        for (int fn = 0; fn < 2; ++fn)
          acc[fm][fn] = __builtin_amdgcn_mfma_f32_16x16x32_bf16(av[fm], bv[fn], acc[fm][fn], 0, 0, 0);
    }
  }
#pragma unroll
  for (int fn = 0; fn < 2; ++fn) {
    int c = n0 + wc * 32 + fn * 16 + (l & 15);
    float bb = bias ? bias[c] : 0.f;
#pragma unroll
    for (int fm = 0; fm < 4; ++fm) {
      int r = m0 + wr * 64 + fm * 16 + (l >> 4) * 4;
#pragma unroll
      for (int j = 0; j < 4; ++j) {
        float val = acc[fm][fn][j] + bb;
        if (B16OUT) ((u16*)outv)[(size_t)(r + j) * ldo + c] = f2b(val);
        else        ((float*)outv)[(size_t)(r + j) * ldo + c] = val;
      }
    }
  }
}

// ---------------- batched logits GEMM: bcat(31744x768) @ Wfc^T -> dout scatter ----
__global__ __launch_bounds__(256) void k_bgemm_logits(const u16* __restrict__ A,
                                                      const u16* __restrict__ B,
                                                      const float* __restrict__ bias,
                                                      float* __restrict__ dout) {
  __shared__ u16 sA[128 * 64];
  __shared__ u16 sB[64 * 64];
  int m0 = blockIdx.x * 128, n0 = blockIdx.y * 64;
  int tid = threadIdx.x, w = tid >> 6, l = tid & 63;
  int wr = w >> 1, wc = w & 1;
  f32x4 acc[4][2] = {};
  for (int k0 = 0; k0 < 768; k0 += 64) {
    __syncthreads();
#pragma unroll
    for (int i = 0; i < 4; ++i) {
      int chunk = i * 4 + w;
      int d = chunk * 1024 + l * 16;
      int lg = d ^ (((d >> 7) & 7) << 4);
      int row = lg >> 7, kb = lg & 127;
      gload16((const char*)(A + (size_t)(m0 + row) * 768 + k0) + kb, (char*)sA + chunk * 1024);
    }
#pragma unroll
    for (int i = 0; i < 2; ++i) {
      int chunk = i * 4 + w;
      int d = chunk * 1024 + l * 16;
      int lg = d ^ (((d >> 7) & 7) << 4);
      int row = lg >> 7, kb = lg & 127;
      gload16((const char*)(B + (size_t)(n0 + row) * 768 + k0) + kb, (char*)sB + chunk * 1024);
    }
    __syncthreads();
#pragma unroll
    for (int kk = 0; kk < 2; ++kk) {
      bf16x8 av[4], bv[2];
#pragma unroll
      for (int fm = 0; fm < 4; ++fm) {
        int row = wr * 64 + fm * 16 + (l & 15);
        int addr = (row * 128 + kk * 64 + (l >> 4) * 16) ^ ((row & 7) << 4);
        av[fm] = *(const bf16x8*)((const char*)sA + addr);
      }
#pragma unroll
      for (int fn = 0; fn < 2; ++fn) {
        int row = wc * 32 + fn * 16 + (l & 15);
        int addr = (row * 128 + kk * 64 + (l >> 4) * 16) ^ ((row & 7) << 4);
        bv[fn] = *(const bf16x8*)((const char*)sB + addr);
      }
#pragma unroll
      for (int fm = 0; fm < 4; ++fm)
#pragma unroll
        for (int fn = 0; fn < 2; ++fn)
          acc[fm][fn] = __builtin_amdgcn_mfma_f32_16x16x32_bf16(av[fm], bv[fn], acc[fm][fn], 0, 0, 0);
    }
  }
#pragma unroll
  for (int fn = 0; fn < 2; ++fn) {
    int c = n0 + wc * 32 + fn * 16 + (l & 15);
    float bb = bias[c];
#pragma unroll
    for (int fm = 0; fm < 4; ++fm) {
#pragma unroll
      for (int j = 0; j < 4; ++j) {
        int gr = m0 + wr * 64 + fm * 16 + (l >> 4) * 4 + j;
        int tt = gr >> 10, b = gr & 1023;
        dout[(size_t)b * (TLEN * 256) + (size_t)(tt + 1) * 256 + c] = acc[fm][fn][j] + bb;
      }
    }
  }
}

// ---------------- persistent encoder: 512 blocks x 2 rows, 16 waves, 2 blk/CU ----
struct EncArgs {
  u16* enc_b; u16* hcatB; const int* src;
  const u16* Whhf; const u16* Whhb;
  const float* bhhf; const float* bhhb;
  const float* tabf; const float* tabb;
};

__global__ __launch_bounds__(1024, 8) void k_enc_p(EncArgs E) {
  __shared__ float hF[2][2 * HFLD];
  __shared__ u16 hB[2][16 * HLD];
  __shared__ int toks[64];
  int r0 = blockIdx.x * 2;
  int tid = threadIdx.x, w = tid >> 6, l = tid & 63;
  int dir = w >> 3, wc = w & 7;
  for (int i = tid; i < 16 * HLD; i += 1024) { hB[0][i] = 0; hB[1][i] = 0; }
  if (tid < 512) {
    int r = tid >> 8, c = tid & 255;
    hF[0][r * HFLD + c] = 0.f; hF[1][r * HFLD + c] = 0.f;
  }
  if (tid < 64) toks[tid] = E.src[(size_t)(r0 + (tid >> 5)) * SLEN + (tid & 31)];
  __syncthreads();
  const u16* Whh = dir ? E.Whhb : E.Whhf;
  const float* tab = dir ? E.tabb : E.tabf;
  const float* bhh = dir ? E.bhhb : E.bhhf;
  for (int s = 0; s < SLEN; ++s) {
    int s_store = dir ? (SLEN - 1 - s) : s;
    f32x4 ae[3][2] = {};
    if (s > 0) {
#pragma unroll
      for (int kk = 0; kk < 8; ++kk) {
        bf16x8 av = *(const bf16x8*)(hB[dir] + (l & 15) * HLD + kk * 32 + (l >> 4) * 8);
#pragma unroll
        for (int g = 0; g < 3; ++g)
#pragma unroll
          for (int fn = 0; fn < 2; ++fn) {
            bf16x8 bv = *(const bf16x8*)(Whh +
                (size_t)(g * 256 + wc * 32 + fn * 16 + (l & 15)) * 256 + kk * 32 + (l >> 4) * 8);
            ae[g][fn] = __builtin_amdgcn_mfma_f32_16x16x32_bf16(av, bv, ae[g][fn], 0, 0, 0);
          }
      }
    }
    __syncthreads();
#pragma unroll
    for (int fn = 0; fn < 2; ++fn) {
      int c = wc * 32 + fn * 16 + (l & 15);
      float bR = bhh[c], bZ = bhh[256 + c], bN = bhh[512 + c];
#pragma unroll
      for (int j = 0; j < 2; ++j) {
        int row = (l >> 4) * 4 + j;
        if ((l >> 4) == 0) {
          const float* tb = tab + (size_t)toks[row * 32 + s_store] * 768 + c;
          float rg = sgm(tb[0] + ae[0][fn][j] + bR);
          float zg = sgm(tb[256] + ae[1][fn][j] + bZ);
          float ng = tanh_fast(tb[512] + rg * (ae[2][fn][j] + bN));
          float hold = hF[dir][row * HFLD + c];
          float hv = (1.f - zg) * ng + zg * hold;
          hF[dir][row * HFLD + c] = hv;
          u16 hb16 = f2b(hv);
          hB[dir][row * HLD + c] = hb16;
          E.enc_b[((size_t)(r0 + row) * SLEN + s_store) * 512 + dir * 256 + c] = hb16;
        }
      }
    }
    __syncthreads();
  }
  for (int i = tid; i < 2 * 512; i += 1024) {
    int r = i >> 9, c = i & 511;
    E.hcatB[(size_t)(r0 + r) * 512 + c] =
        (c < 256) ? hB[0][r * HLD + c] : hB[1][r * HLD + (c - 256)];
  }
}

// ---------------- persistent decoder: 512 blocks x 2 rows, 2 blk/CU --------------
// LDS layout (~73KB). MFMA A-fragments over-read rows 2-15 of hB/ctxB; those
// addresses land in later LDS regions — D rows 2-15 never read, safe.
#define OFF_HB    0                     // 2 * HLD u16        = 1064 -> 1072
#define OFF_CTX   1072                  // 2 * CTXLD u16      = 2088 -> 2096
#define OFF_HF    3168                  // 2 * HFLD f32       = 2080
#define OFF_HW    5248                  // 2 * HWLD f32       = 2080
#define OFF_AW    7328                  // 2*33 f32           = 264 -> 272
#define OFF_SC    7600                  // 2*32 f32           = 256
#define OFF_VS    7856                  // 256 f32            = 1024
#define OFF_TOK   8880                  // 64 int             = 256
#define OFF_EB    9136                  // 2*32*512 u16       = 65536
#define SMEM_TOT  74672

struct DecArgs {
  const u16* enc_b; const u16* enc_pre_b; const float* v_attn;
  const u16* Wd_b; const u16* Wg_lo; const u16* Wg_hi;
  const float* tabd; const float* dbhh;
  const int* trg; const float* h0f;
  u16* bcat;
};

__global__ __launch_bounds__(1024, 8) void k_dec_p(DecArgs A) {
  __shared__ __align__(16) char smem[SMEM_TOT];
  u16* hB = (u16*)(smem + OFF_HB);
  u16* ctxB = (u16*)(smem + OFF_CTX);
  float* hF = (float*)(smem + OFF_HF);
  float* hwS = (float*)(smem + OFF_HW);
  float* awS = (float*)(smem + OFF_AW);
  float* scS = (float*)(smem + OFF_SC);
  float* vS = (float*)(smem + OFF_VS);
  int* toks = (int*)(smem + OFF_TOK);
  u16* ebL = (u16*)(smem + OFF_EB);
  int r0 = blockIdx.x * 2;
  int tid = threadIdx.x, w = tid >> 6, l = tid & 63;
  // stage enc_b slice (2 rows x 32 s x 512) into LDS, swizzled 16B chunks
  {
    const u16* src = A.enc_b + (size_t)r0 * SLEN * 512;
#pragma unroll
    for (int i = 0; i < 4; ++i) {
      int idx = (tid + i * 1024) * 8;
      int srow = idx >> 9;                 // r*32 + s
      int chunk = (idx & 511) >> 3;        // 0..63
      int swz = (srow >> 2) & 7;
      bf16x8 v = *(const bf16x8*)(src + idx);
      *(bf16x8*)(ebL + srow * 512 + ((chunk ^ swz) << 3)) = v;
    }
  }
  if (tid < 512) {
    int r = tid >> 8, c = tid & 255;
    float v = A.h0f[(size_t)(r0 + r) * 256 + c];
    hF[r * HFLD + c] = v;
    hB[r * HLD + c] = f2b(v);
  }
  if (tid < 256) vS[tid] = A.v_attn[tid];
  if (tid < 64) toks[tid] = A.trg[(size_t)(r0 + (tid >> 5)) * TLEN + (tid & 31)];
  __syncthreads();
  for (int t = 0; t < TLEN - 1; ++t) {
    // ---- P1: hWd = h @ Wd^T : wave w -> cols [w*16, w*16+16) ----
    {
      f32x4 a1 = {};
#pragma unroll
      for (int kk = 0; kk < 8; ++kk) {
        bf16x8 av = *(const bf16x8*)(hB + (l & 15) * HLD + kk * 32 + (l >> 4) * 8);
        bf16x8 bv = *(const bf16x8*)(A.Wd_b + (size_t)(w * 16 + (l & 15)) * 256 + kk * 32 + (l >> 4) * 8);
        a1 = __builtin_amdgcn_mfma_f32_16x16x32_bf16(av, bv, a1, 0, 0, 0);
      }
      int c = w * 16 + (l & 15);
      if ((l >> 4) == 0) {
#pragma unroll
        for (int j = 0; j < 2; ++j) hwS[j * HWLD + c] = a1[j];
      }
    }
    __syncthreads();
    // ---- P2: scores: r = tid>>9, s = (tid>>4)&31, part = tid&15 ----
    {
      int r = tid >> 9, s = (tid >> 4) & 31, part = tid & 15;
      const u16* ep = A.enc_pre_b + ((size_t)(r0 + r) * SLEN + s) * 256 + part * 16;
      const float* hw = hwS + r * HWLD + part * 16;
      const float* vv = vS + part * 16;
      float sum = 0.f;
#pragma unroll
      for (int a0 = 0; a0 < 16; a0 += 8) {
        bf16x8 pk = *(const bf16x8*)(ep + a0);
#pragma unroll
        for (int q = 0; q < 8; ++q)
          sum += vv[a0 + q] * tanh_fast(b2f((u16)pk[q]) + hw[a0 + q]);
      }
      sum += __shfl_xor(sum, 1);
      sum += __shfl_xor(sum, 2);
      sum += __shfl_xor(sum, 4);
      sum += __shfl_xor(sum, 8);
      if (part == 0) scS[r * 32 + s] = sum;
    }
    __syncthreads();
    // softmax over s: tid<64, r = tid>>5, s = tid&31
    if (tid < 64) {
      int r = tid >> 5, s = tid & 31;
      float v = scS[r * 32 + s], m = v;
#pragma unroll
      for (int o = 1; o <= 16; o <<= 1) m = fmaxf(m, __shfl_xor(m, o));
      float e = __expf(v - m), ss = e;
#pragma unroll
      for (int o = 1; o <= 16; o <<= 1) ss += __shfl_xor(ss, o);
      awS[r * 33 + s] = e / ss;
    }
    __syncthreads();
    // ---- P3: ctx from ebL: r = tid>>9, ch = (tid>>3)&63, sp = tid&7 ----
    {
      int r = tid >> 9, ch = (tid >> 3) & 63, sp = tid & 7;
      int c = ch * 8;
      float a8[8] = {};
#pragma unroll
      for (int s2 = 0; s2 < 4; ++s2) {
        int s = sp * 4 + s2;
        float a = awS[r * 33 + s];
        bf16x8 pk = *(const bf16x8*)(ebL + (r * 32 + s) * 512 + ((ch ^ sp) << 3));
#pragma unroll
        for (int q = 0; q < 8; ++q) a8[q] += a * b2f((u16)pk[q]);
      }
#pragma unroll
      for (int o = 1; o <= 4; o <<= 1)
#pragma unroll
        for (int q = 0; q < 8; ++q) a8[q] += __shfl_xor(a8[q], o);
      if (sp == 0) {
        bf16x8 o;
#pragma unroll
        for (int q = 0; q < 8; ++q) o[q] = (short)f2b(a8[q]);
        *(bf16x8*)(ctxB + r * CTXLD + c) = o;
        *(bf16x8*)(A.bcat + ((size_t)t * BSZ + r0 + r) * 768 + 256 + c) = o;
      }
    }
    __syncthreads();
    // ---- P4: gates: wave w -> hidden cols [w*16, +16), plain loads, TLP-hidden --
    f32x4 ag[4] = {};
#pragma unroll
    for (int kk = 0; kk < 24; ++kk) {
      bf16x8 av = (kk < 16)
          ? *(const bf16x8*)(ctxB + (l & 15) * CTXLD + kk * 32 + (l >> 4) * 8)
          : *(const bf16x8*)(hB + (l & 15) * HLD + (kk - 16) * 32 + (l >> 4) * 8);
#pragma unroll
      for (int gb = 0; gb < 3; ++gb) {
        bf16x8 bv;
        if (kk < 16)
          bv = *(const bf16x8*)(A.Wg_lo +
              (size_t)(gb * 256 + w * 16 + (l & 15)) * 512 + kk * 32 + (l >> 4) * 8);
        else
          bv = *(const bf16x8*)(A.Wg_hi +
              (size_t)(gb * 256 + w * 16 + (l & 15)) * 256 + (kk - 16) * 32 + (l >> 4) * 8);
        int ai = (kk < 16) ? gb : (gb == 2 ? 3 : gb);
        ag[ai] = __builtin_amdgcn_mfma_f32_16x16x32_bf16(av, bv, ag[ai], 0, 0, 0);
      }
    }
    __syncthreads();
    // ---- P5: GRU epilogue: wave w -> col c = w*16 + (l&15), rows < 2 ----
    {
      int c = w * 16 + (l & 15);
      float bR = A.dbhh[c], bZ = A.dbhh[256 + c], bN = A.dbhh[512 + c];
      if ((l >> 4) == 0) {
#pragma unroll
        for (int j = 0; j < 2; ++j) {
          int row = j;
          const float* tb = A.tabd + (size_t)toks[row * 32 + t] * 768 + c;
          float rg = sgm(tb[0] + ag[0][j] + bR);
          float zg = sgm(tb[256] + ag[1][j] + bZ);
          float ng = tanh_fast(tb[512] + ag[2][j] + rg * (ag[3][j] + bN));
          float hold = hF[row * HFLD + c];
          float hv = (1.f - zg) * ng + zg * hold;
          hF[row * HFLD + c] = hv;
          u16 hb16 = f2b(hv);
          hB[row * HLD + c] = hb16;
          A.bcat[((size_t)t * BSZ + r0 + row) * 768 + c] = hb16;
        }
      }
    }
    __syncthreads();
  }
}

// ---------------- zero t=0 slice -------------------------------------------------
__global__ __launch_bounds__(256) void k_zero0(float* __restrict__ outp) {
  outp[(size_t)blockIdx.x * (TLEN * 256) + threadIdx.x] = 0.f;
}

extern "C" void kernel_launch(void* const* d_in, const int* in_sizes, int n_in,
                              void* d_out, int out_size, void* d_ws, size_t ws_size,
                              hipStream_t stream) {
  (void)in_sizes; (void)n_in; (void)out_size; (void)ws_size;
  const int* src = (const int*)d_in[0];
  const int* trg = (const int*)d_in[1];
  const float* enc_emb = (const float*)d_in[2];
  const float* eWih_f = (const float*)d_in[3];
  const float* eWhh_f = (const float*)d_in[4];
  const float* ebih_f = (const float*)d_in[5];
  const float* ebhh_f = (const float*)d_in[6];
  const float* eWih_b = (const float*)d_in[7];
  const float* eWhh_b = (const float*)d_in[8];
  const float* ebih_b = (const float*)d_in[9];
  const float* ebhh_b = (const float*)d_in[10];
  const float* Wproj = (const float*)d_in[11];
  const float* bproj = (const float*)d_in[12];
  const float* dec_emb = (const float*)d_in[13];
  const float* Wattn = (const float*)d_in[14];
  const float* battn = (const float*)d_in[15];
  const float* v_attn = (const float*)d_in[16];
  const float* dWih = (const float*)d_in[17];
  const float* dWhh = (const float*)d_in[18];
  const float* dbih = (const float*)d_in[19];
  const float* dbhh = (const float*)d_in[20];
  const float* Wfc = (const float*)d_in[21];
  const float* bfc = (const float*)d_in[22];
  float* dout = (float*)d_out;

  char* base = (char*)d_ws;
  size_t off = 0;
  auto alloc = [&](size_t bytes) {
    void* p = base + off;
    off += (bytes + 255) & ~(size_t)255;
    return p;
  };
  u16* enc_b     = (u16*)alloc((size_t)BSZ * SLEN * 512 * 2);
  u16* enc_pre_b = (u16*)alloc((size_t)BSZ * SLEN * 256 * 2);
  u16* bcat      = (u16*)alloc((size_t)31 * BSZ * 768 * 2);
  float* tabf    = (float*)alloc((size_t)64 * 768 * 4);
  float* tabb    = (float*)alloc((size_t)64 * 768 * 4);
  float* tabd    = (float*)alloc((size_t)256 * 768 * 4);
  u16* hcatB     = (u16*)alloc((size_t)BSZ * 512 * 2);
  float* h0f     = (float*)alloc((size_t)BSZ * 256 * 4);
  u16* Whhf_b    = (u16*)alloc((size_t)768 * 256 * 2);
  u16* Whhb_b    = (u16*)alloc((size_t)768 * 256 * 2);
  u16* We_b      = (u16*)alloc((size_t)256 * 512 * 2);
  u16* Wd_b      = (u16*)alloc((size_t)256 * 256 * 2);
  u16* Wproj_b   = (u16*)alloc((size_t)256 * 512 * 2);
  u16* Wg_lo     = (u16*)alloc((size_t)768 * 512 * 2);
  u16* Wg_hi     = (u16*)alloc((size_t)768 * 256 * 2);
  u16* Wfc_b     = (u16*)alloc((size_t)256 * 768 * 2);

  // tables + weight packs
  k_gi_table<<<dim3(64, 3), 256, 0, stream>>>(enc_emb, eWih_f, EDIM, ebih_f, tabf);
  k_gi_table<<<dim3(64, 3), 256, 0, stream>>>(enc_emb, eWih_b, EDIM, ebih_b, tabb);
  k_gi_table<<<dim3(256, 3), 256, 0, stream>>>(dec_emb, dWih, 640, dbih, tabd);
  k_pack<<<dim3(768), 256, 0, stream>>>(Whhf_b, eWhh_f, 256, 0, 256);
  k_pack<<<dim3(768), 256, 0, stream>>>(Whhb_b, eWhh_b, 256, 0, 256);
  k_pack<<<dim3(256), 256, 0, stream>>>(We_b, Wattn, 768, 256, 512);
  k_pack<<<dim3(256), 256, 0, stream>>>(Wd_b, Wattn, 768, 0, 256);
  k_pack<<<dim3(256), 256, 0, stream>>>(Wproj_b, Wproj, 512, 0, 512);
  k_pack<<<dim3(768), 256, 0, stream>>>(Wg_lo, dWih, 640, 128, 512);
  k_pack<<<dim3(768), 256, 0, stream>>>(Wg_hi, dWhh, 256, 0, 256);
  k_pack<<<dim3(256), 256, 0, stream>>>(Wfc_b, Wfc, 768, 0, 768);

  // encoder: persistent, 512 blocks x 2 rows, 2 blocks/CU
  {
    EncArgs ea{enc_b, hcatB, src, Whhf_b, Whhb_b, ebhh_f, ebhh_b, tabf, tabb};
    k_enc_p<<<dim3(512), dim3(1024), 0, stream>>>(ea);
  }

  // hdec = hcat @ Wproj^T + bproj (fp32 out)
  k_bgemm<false><<<dim3(8, 4), 256, 0, stream>>>(hcatB, 512, Wproj_b, 512, bproj, h0f, 256, 512);
  // enc_pre (bf16) = enc_b @ We^T + battn
  k_bgemm<true><<<dim3(256, 4), 256, 0, stream>>>(enc_b, 512, We_b, 512, battn,
                                                  enc_pre_b, 256, 512);
  k_zero0<<<dim3(BSZ), 256, 0, stream>>>(dout);

  // decoder: persistent, 512 blocks x 2 rows, 2 blocks/CU
  {
    DecArgs da{enc_b, enc_pre_b, v_attn, Wd_b, Wg_lo, Wg_hi, tabd, dbhh, trg, h0f, bcat};
    k_dec_p<<<dim3(512), dim3(1024), 0, stream>>>(da);
  }

  // deferred logits: [hn|ctx] @ Wfc^T + bfc for all 31 steps at once
  k_bgemm_logits<<<dim3(248, 4), 256, 0, stream>>>(bcat, Wfc_b, bfc, dout);
}

// Round 14
// 2417.665 us; speedup vs baseline: 2.0633x; 2.0633x over previous
//
#include <hip/hip_runtime.h>
#include <math.h>

#define BSZ 1024
#define SLEN 32
#define TLEN 32
#define EDIM 128
#define HLD 266    // u16 row stride (odd dwords -> conflict-free col reads)
#define HFLD 260   // f32 row stride
#define CTXLD 522  // u16 row stride
#define HWLD 260   // f32 row stride

typedef unsigned short u16;
typedef __attribute__((ext_vector_type(8))) short bf16x8;
typedef __attribute__((ext_vector_type(4))) float f32x4;

__device__ __forceinline__ float sgm(float x) { return 1.0f / (1.0f + __expf(-x)); }
__device__ __forceinline__ float tanh_fast(float x) {
  float e = __expf(-2.0f * fabsf(x));
  float t = (1.0f - e) / (1.0f + e);
  return copysignf(t, x);
}
__device__ __forceinline__ u16 f2b(float f) {
  union { float f; unsigned u; } v; v.f = f;
  unsigned r = v.u + 0x7fffu + ((v.u >> 16) & 1u);
  return (u16)(r >> 16);
}
__device__ __forceinline__ float b2f(u16 h) {
  union { unsigned u; float f; } v; v.u = ((unsigned)h) << 16; return v.f;
}

typedef __attribute__((address_space(1))) const void gv_t;
typedef __attribute__((address_space(3))) void lv_t;
__device__ __forceinline__ void gload16(const void* g, void* l) {
  __builtin_amdgcn_global_load_lds((gv_t*)g, (lv_t*)l, 16, 0, 0);
}

// ---------------- gi tables -------------------------------------------------------
__global__ __launch_bounds__(256) void k_gi_table(const float* __restrict__ emb,
                                                  const float* __restrict__ Wih, int ldw,
                                                  const float* __restrict__ bih,
                                                  float* __restrict__ tab) {
  int v = blockIdx.x;
  int g = blockIdx.y * 256 + threadIdx.x;
  __shared__ float e[EDIM];
  if (threadIdx.x < EDIM) e[threadIdx.x] = emb[v * EDIM + threadIdx.x];
  __syncthreads();
  const float4* w4 = (const float4*)(Wih + (size_t)g * ldw);
  float acc = 0.f;
#pragma unroll
  for (int j = 0; j < EDIM / 4; ++j) {
    float4 w = w4[j];
    acc += w.x * e[4 * j] + w.y * e[4 * j + 1] + w.z * e[4 * j + 2] + w.w * e[4 * j + 3];
  }
  tab[(size_t)v * 768 + g] = acc + bih[g];
}

// ---------------- gi pre-gather: gi[t][b][:] = tabd[trg[b][t]][:] ----------------
__global__ __launch_bounds__(256) void k_gather(const float* __restrict__ tabd,
                                                const int* __restrict__ trg,
                                                float* __restrict__ gi) {
  int t = blockIdx.x, b = blockIdx.y;
  int tok = trg[(size_t)b * TLEN + t];
  const float* src = tabd + (size_t)tok * 768;
  float* dst = gi + ((size_t)t * BSZ + b) * 768;
  for (int g = threadIdx.x; g < 768; g += 256) dst[g] = src[g];
}

// ---------------- fp32 -> bf16 weight pack ---------------------------------------
__global__ __launch_bounds__(256) void k_pack(u16* __restrict__ dst,
                                              const float* __restrict__ src, int ld,
                                              int off, int n) {
  int r = blockIdx.x;
  for (int c = threadIdx.x; c < n; c += 256)
    dst[(size_t)r * n + c] = f2b(src[(size_t)r * ld + off + c]);
}

// ---------------- bf16 MFMA GEMM 128x64: out = A.B^T + bias ----------------------
template <bool B16OUT>
__global__ __launch_bounds__(256) void k_bgemm(const u16* __restrict__ A, int lda,
                                               const u16* __restrict__ B, int ldb,
                                               const float* __restrict__ bias,
                                               void* __restrict__ outv, int ldo, int K) {
  __shared__ u16 sA[128 * 64];
  __shared__ u16 sB[64 * 64];
  int m0 = blockIdx.x * 128, n0 = blockIdx.y * 64;
  int tid = threadIdx.x, w = tid >> 6, l = tid & 63;
  int wr = w >> 1, wc = w & 1;
  f32x4 acc[4][2] = {};
  for (int k0 = 0; k0 < K; k0 += 64) {
    __syncthreads();
#pragma unroll
    for (int i = 0; i < 4; ++i) {
      int chunk = i * 4 + w;
      int d = chunk * 1024 + l * 16;
      int lg = d ^ (((d >> 7) & 7) << 4);
      int row = lg >> 7, kb = lg & 127;
      gload16((const char*)(A + (size_t)(m0 + row) * lda + k0) + kb, (char*)sA + chunk * 1024);
    }
#pragma unroll
    for (int i = 0; i < 2; ++i) {
      int chunk = i * 4 + w;
      int d = chunk * 1024 + l * 16;
      int lg = d ^ (((d >> 7) & 7) << 4);
      int row = lg >> 7, kb = lg & 127;
      gload16((const char*)(B + (size_t)(n0 + row) * ldb + k0) + kb, (char*)sB + chunk * 1024);
    }
    __syncthreads();
#pragma unroll
    for (int kk = 0; kk < 2; ++kk) {
      bf16x8 av[4], bv[2];
#pragma unroll
      for (int fm = 0; fm < 4; ++fm) {
        int row = wr * 64 + fm * 16 + (l & 15);
        int addr = (row * 128 + kk * 64 + (l >> 4) * 16) ^ ((row & 7) << 4);
        av[fm] = *(const bf16x8*)((const char*)sA + addr);
      }
#pragma unroll
      for (int fn = 0; fn < 2; ++fn) {
        int row = wc * 32 + fn * 16 + (l & 15);
        int addr = (row * 128 + kk * 64 + (l >> 4) * 16) ^ ((row & 7) << 4);
        bv[fn] = *(const bf16x8*)((const char*)sB + addr);
      }
#pragma unroll
      for (int fm = 0; fm < 4; ++fm)
#pragma unroll
        for (int fn = 0; fn < 2; ++fn)
          acc[fm][fn] = __builtin_amdgcn_mfma_f32_16x16x32_bf16(av[fm], bv[fn], acc[fm][fn], 0, 0, 0);
    }
  }
#pragma unroll
  for (int fn = 0; fn < 2; ++fn) {
    int c = n0 + wc * 32 + fn * 16 + (l & 15);
    float bb = bias ? bias[c] : 0.f;
#pragma unroll
    for (int fm = 0; fm < 4; ++fm) {
      int r = m0 + wr * 64 + fm * 16 + (l >> 4) * 4;
#pragma unroll
      for (int j = 0; j < 4; ++j) {
        float val = acc[fm][fn][j] + bb;
        if (B16OUT) ((u16*)outv)[(size_t)(r + j) * ldo + c] = f2b(val);
        else        ((float*)outv)[(size_t)(r + j) * ldo + c] = val;
      }
    }
  }
}

// ---------------- batched logits GEMM: bcat(31744x768) @ Wfc^T -> dout scatter ----
__global__ __launch_bounds__(256) void k_bgemm_logits(const u16* __restrict__ A,
                                                      const u16* __restrict__ B,
                                                      const float* __restrict__ bias,
                                                      float* __restrict__ dout) {
  __shared__ u16 sA[128 * 64];
  __shared__ u16 sB[64 * 64];
  int m0 = blockIdx.x * 128, n0 = blockIdx.y * 64;
  int tid = threadIdx.x, w = tid >> 6, l = tid & 63;
  int wr = w >> 1, wc = w & 1;
  f32x4 acc[4][2] = {};
  for (int k0 = 0; k0 < 768; k0 += 64) {
    __syncthreads();
#pragma unroll
    for (int i = 0; i < 4; ++i) {
      int chunk = i * 4 + w;
      int d = chunk * 1024 + l * 16;
      int lg = d ^ (((d >> 7) & 7) << 4);
      int row = lg >> 7, kb = lg & 127;
      gload16((const char*)(A + (size_t)(m0 + row) * 768 + k0) + kb, (char*)sA + chunk * 1024);
    }
#pragma unroll
    for (int i = 0; i < 2; ++i) {
      int chunk = i * 4 + w;
      int d = chunk * 1024 + l * 16;
      int lg = d ^ (((d >> 7) & 7) << 4);
      int row = lg >> 7, kb = lg & 127;
      gload16((const char*)(B + (size_t)(n0 + row) * 768 + k0) + kb, (char*)sB + chunk * 1024);
    }
    __syncthreads();
#pragma unroll
    for (int kk = 0; kk < 2; ++kk) {
      bf16x8 av[4], bv[2];
#pragma unroll
      for (int fm = 0; fm < 4; ++fm) {
        int row = wr * 64 + fm * 16 + (l & 15);
        int addr = (row * 128 + kk * 64 + (l >> 4) * 16) ^ ((row & 7) << 4);
        av[fm] = *(const bf16x8*)((const char*)sA + addr);
      }
#pragma unroll
      for (int fn = 0; fn < 2; ++fn) {
        int row = wc * 32 + fn * 16 + (l & 15);
        int addr = (row * 128 + kk * 64 + (l >> 4) * 16) ^ ((row & 7) << 4);
        bv[fn] = *(const bf16x8*)((const char*)sB + addr);
      }
#pragma unroll
      for (int fm = 0; fm < 4; ++fm)
#pragma unroll
        for (int fn = 0; fn < 2; ++fn)
          acc[fm][fn] = __builtin_amdgcn_mfma_f32_16x16x32_bf16(av[fm], bv[fn], acc[fm][fn], 0, 0, 0);
    }
  }
#pragma unroll
  for (int fn = 0; fn < 2; ++fn) {
    int c = n0 + wc * 32 + fn * 16 + (l & 15);
    float bb = bias[c];
#pragma unroll
    for (int fm = 0; fm < 4; ++fm) {
#pragma unroll
      for (int j = 0; j < 4; ++j) {
        int gr = m0 + wr * 64 + fm * 16 + (l >> 4) * 4 + j;
        int tt = gr >> 10, b = gr & 1023;
        dout[(size_t)b * (TLEN * 256) + (size_t)(tt + 1) * 256 + c] = acc[fm][fn][j] + bb;
      }
    }
  }
}

// ---------------- persistent encoder: 256 blocks x 4 rows, 16 waves --------------
struct EncArgs {
  u16* enc_b; u16* hcatB; const int* src;
  const u16* Whhf; const u16* Whhb;
  const float* bhhf; const float* bhhb;
  const float* tabf; const float* tabb;
};

__global__ __launch_bounds__(1024, 4) void k_enc_p(EncArgs E) {
  __shared__ float hF[2][4 * HFLD];
  __shared__ u16 hB[2][16 * HLD];
  __shared__ int toks[128];
  int r0 = blockIdx.x * 4;
  int tid = threadIdx.x, w = tid >> 6, l = tid & 63;
  int dir = w >> 3, wc = w & 7;  // wave: direction + 32-col slice
  for (int i = tid; i < 16 * HLD; i += 1024) { hB[0][i] = 0; hB[1][i] = 0; }
  __syncthreads();
  if (tid < 1024) {
    int r = tid >> 8, c = tid & 255;
    hF[0][r * HFLD + c] = 0.f; hF[1][r * HFLD + c] = 0.f;
  }
  if (tid < 128) toks[tid] = E.src[(size_t)(r0 + (tid >> 5)) * SLEN + (tid & 31)];
  __syncthreads();
  const u16* Whh = dir ? E.Whhb : E.Whhf;
  const float* tab = dir ? E.tabb : E.tabf;
  const float* bhh = dir ? E.bhhb : E.bhhf;
  for (int s = 0; s < SLEN; ++s) {
    int s_store = dir ? (SLEN - 1 - s) : s;
    f32x4 ae[3][2] = {};
    if (s > 0) {
#pragma unroll
      for (int kk = 0; kk < 8; ++kk) {
        bf16x8 av = *(const bf16x8*)(hB[dir] + (l & 15) * HLD + kk * 32 + (l >> 4) * 8);
#pragma unroll
        for (int g = 0; g < 3; ++g)
#pragma unroll
          for (int fn = 0; fn < 2; ++fn) {
            bf16x8 bv = *(const bf16x8*)(Whh +
                (size_t)(g * 256 + wc * 32 + fn * 16 + (l & 15)) * 256 + kk * 32 + (l >> 4) * 8);
            ae[g][fn] = __builtin_amdgcn_mfma_f32_16x16x32_bf16(av, bv, ae[g][fn], 0, 0, 0);
          }
      }
    }
    __syncthreads();
#pragma unroll
    for (int fn = 0; fn < 2; ++fn) {
      int c = wc * 32 + fn * 16 + (l & 15);
      float bR = bhh[c], bZ = bhh[256 + c], bN = bhh[512 + c];
#pragma unroll
      for (int j = 0; j < 4; ++j) {
        int row = (l >> 4) * 4 + j;
        if (row < 4) {
          const float* tb = tab + (size_t)toks[row * 32 + s_store] * 768 + c;
          float rg = sgm(tb[0] + ae[0][fn][j] + bR);
          float zg = sgm(tb[256] + ae[1][fn][j] + bZ);
          float ng = tanh_fast(tb[512] + rg * (ae[2][fn][j] + bN));
          float hold = hF[dir][row * HFLD + c];
          float hv = (1.f - zg) * ng + zg * hold;
          hF[dir][row * HFLD + c] = hv;
          u16 hb16 = f2b(hv);
          hB[dir][row * HLD + c] = hb16;
          E.enc_b[((size_t)(r0 + row) * SLEN + s_store) * 512 + dir * 256 + c] = hb16;
        }
      }
    }
    __syncthreads();
  }
  for (int i = tid; i < 4 * 512; i += 1024) {
    int r = i >> 9, c = i & 511;
    E.hcatB[(size_t)(r0 + r) * 512 + c] =
        (c < 256) ? hB[0][r * HLD + c] : hB[1][r * HLD + (c - 256)];
  }
}

// ---------------- persistent decoder: 256 blocks x 4 rows, 4 barriers/step -------
#define OFF_HB    0                     // 4 * HLD u16
#define OFF_CTX   2128                  // 4 * CTXLD u16
#define OFF_HF    6304                  // 4 * HFLD f32
#define OFF_HW    10464                 // 4 * HWLD f32
#define OFF_AW    14624                 // 4*33 f32
#define OFF_VS    15664                 // 256 f32
#define OFF_EB    17200                 // 4*32*512 u16 = 131072
#define SMEM_TOT  148272

struct DecArgs {
  const u16* enc_b; const u16* enc_pre_b; const float* v_attn;
  const u16* Wd_b; const u16* Wg_lo; const u16* Wg_hi;
  const float* dbhh; const float* gi;
  const float* h0f;
  u16* bcat;
};

__global__ __launch_bounds__(1024, 4) void k_dec_p(DecArgs A) {
  __shared__ __align__(16) char smem[SMEM_TOT];
  u16* hB = (u16*)(smem + OFF_HB);
  u16* ctxB = (u16*)(smem + OFF_CTX);
  float* hF = (float*)(smem + OFF_HF);
  float* hwS = (float*)(smem + OFF_HW);
  float* awS = (float*)(smem + OFF_AW);
  float* vS = (float*)(smem + OFF_VS);
  u16* ebL = (u16*)(smem + OFF_EB);
  int r0 = blockIdx.x * 4;
  int tid = threadIdx.x, w = tid >> 6, l = tid & 63;
  // stage enc_b slice (4 rows x 32 s x 512) into LDS, sp-XOR-swizzled chunks
  {
    const u16* src = A.enc_b + (size_t)r0 * SLEN * 512;
#pragma unroll
    for (int i = 0; i < 8; ++i) {
      int idx = (tid + i * 1024) * 8;
      int srow = idx >> 9;
      int chunk = (idx & 511) >> 3;
      int sp = (srow >> 3) & 3;
      bf16x8 v = *(const bf16x8*)(src + idx);
      *(bf16x8*)(ebL + srow * 512 + ((chunk ^ sp) << 3)) = v;
    }
  }
  {
    int r = tid >> 8, c = tid & 255;
    float v = A.h0f[(size_t)(r0 + r) * 256 + c];
    hF[r * HFLD + c] = v;
    hB[r * HLD + c] = f2b(v);
  }
  if (tid < 256) vS[tid] = A.v_attn[tid];
  __syncthreads();
  for (int t = 0; t < TLEN - 1; ++t) {
    // ---- Phase A: prefetch enc_pre (waves 0-3) + merged hWd & gates-h ----
    bf16x8 pf2[8];
    if (w < 4) {
      int s = l >> 1, half = l & 1;
      const u16* ep = A.enc_pre_b + ((size_t)(r0 + w) * SLEN + s) * 256 + half * 128;
#pragma unroll
      for (int i = 0; i < 8; ++i) pf2[i] = *(const bf16x8*)(ep + i * 8);
    }
    f32x4 aAtt = {};
    f32x4 ag[4] = {};  // 0:R 1:Z 2:Ni(ctx) 3:Nh(h)
#pragma unroll
    for (int kk = 0; kk < 8; ++kk) {
      bf16x8 av = *(const bf16x8*)(hB + (l & 15) * HLD + kk * 32 + (l >> 4) * 8);
      bf16x8 b0 = *(const bf16x8*)(A.Wd_b + (size_t)(w * 16 + (l & 15)) * 256 + kk * 32 + (l >> 4) * 8);
      aAtt = __builtin_amdgcn_mfma_f32_16x16x32_bf16(av, b0, aAtt, 0, 0, 0);
#pragma unroll
      for (int gb = 0; gb < 3; ++gb) {
        bf16x8 bv = *(const bf16x8*)(A.Wg_hi +
            (size_t)(gb * 256 + w * 16 + (l & 15)) * 256 + kk * 32 + (l >> 4) * 8);
        int ai = (gb == 2) ? 3 : gb;
        ag[ai] = __builtin_amdgcn_mfma_f32_16x16x32_bf16(av, bv, ag[ai], 0, 0, 0);
      }
    }
    {
      int c = w * 16 + (l & 15);
#pragma unroll
      for (int j = 0; j < 4; ++j) {
        int row = (l >> 4) * 4 + j;
        if (row < 4) hwS[row * HWLD + c] = aAtt[j];
      }
    }
    __syncthreads();
    // ---- P2: scores + in-wave softmax (waves 0-3; row = w) ----
    if (w < 4) {
      int r = w, s = l >> 1, half = l & 1;
      const float* hw = hwS + r * HWLD + half * 128;
      const float* vv = vS + half * 128;
      float sum = 0.f;
#pragma unroll
      for (int i = 0; i < 8; ++i) {
        bf16x8 pk = pf2[i];
#pragma unroll
        for (int q = 0; q < 8; ++q)
          sum += vv[i * 8 + q] * tanh_fast(b2f((u16)pk[q]) + hw[i * 8 + q]);
      }
      const u16* ep = A.enc_pre_b + ((size_t)(r0 + r) * SLEN + s) * 256 + half * 128 + 64;
#pragma unroll
      for (int i = 0; i < 8; ++i) {
        bf16x8 pk = *(const bf16x8*)(ep + i * 8);
#pragma unroll
        for (int q = 0; q < 8; ++q)
          sum += vv[64 + i * 8 + q] * tanh_fast(b2f((u16)pk[q]) + hw[64 + i * 8 + q]);
      }
      sum += __shfl_xor(sum, 1);
      float m = sum;
#pragma unroll
      for (int o = 2; o <= 32; o <<= 1) m = fmaxf(m, __shfl_xor(m, o));
      float e = __expf(sum - m), ss = e;
#pragma unroll
      for (int o = 2; o <= 32; o <<= 1) ss += __shfl_xor(ss, o);
      if (half == 0) awS[r * 33 + s] = e / ss;
    }
    __syncthreads();
    // ---- P3: ctx from ebL: (r = tid>>8, ch = (tid>>2)&63, sp = tid&3) ----
    {
      int r = tid >> 8, ch = (tid >> 2) & 63, sp = tid & 3;
      int c = ch * 8;
      float a8[8] = {};
      const u16* eb = ebL + (r * 32 + sp * 8) * 512 + ((ch ^ sp) << 3);
#pragma unroll
      for (int s2 = 0; s2 < 8; ++s2) {
        float a = awS[r * 33 + sp * 8 + s2];
        bf16x8 pk = *(const bf16x8*)(eb + s2 * 512);
#pragma unroll
        for (int q = 0; q < 8; ++q) a8[q] += a * b2f((u16)pk[q]);
      }
#pragma unroll
      for (int o = 1; o <= 2; o <<= 1)
#pragma unroll
        for (int q = 0; q < 8; ++q) a8[q] += __shfl_xor(a8[q], o);
      if (sp == 0) {
        bf16x8 o;
#pragma unroll
        for (int q = 0; q < 8; ++q) o[q] = (short)f2b(a8[q]);
        *(bf16x8*)(ctxB + r * CTXLD + c) = o;
        *(bf16x8*)(A.bcat + ((size_t)t * BSZ + r0 + r) * 768 + 256 + c) = o;
      }
    }
    __syncthreads();
    // ---- Phase C: gates-ctx, 16 kk, accumulate into ag ----
#pragma unroll
    for (int kk = 0; kk < 16; ++kk) {
      bf16x8 av = *(const bf16x8*)(ctxB + (l & 15) * CTXLD + kk * 32 + (l >> 4) * 8);
#pragma unroll
      for (int gb = 0; gb < 3; ++gb) {
        bf16x8 bv = *(const bf16x8*)(A.Wg_lo +
            (size_t)(gb * 256 + w * 16 + (l & 15)) * 512 + kk * 32 + (l >> 4) * 8);
        ag[gb] = __builtin_amdgcn_mfma_f32_16x16x32_bf16(av, bv, ag[gb], 0, 0, 0);
      }
    }
    // ---- Phase D: GRU epilogue with pregathered gi (coalesced) ----
    {
      int c = w * 16 + (l & 15);
      float bR = A.dbhh[c], bZ = A.dbhh[256 + c], bN = A.dbhh[512 + c];
      const float* gbase = A.gi + ((size_t)t * BSZ + r0) * 768;
#pragma unroll
      for (int j = 0; j < 4; ++j) {
        int row = (l >> 4) * 4 + j;
        if (row < 4) {
          const float* tb = gbase + (size_t)row * 768;
          float rg = sgm(tb[c] + ag[0][j] + bR);
          float zg = sgm(tb[256 + c] + ag[1][j] + bZ);
          float ng = tanh_fast(tb[512 + c] + ag[2][j] + rg * (ag[3][j] + bN));
          float hold = hF[row * HFLD + c];
          float hv = (1.f - zg) * ng + zg * hold;
          hF[row * HFLD + c] = hv;
          u16 hb16 = f2b(hv);
          hB[row * HLD + c] = hb16;
          A.bcat[((size_t)t * BSZ + r0 + row) * 768 + c] = hb16;
        }
      }
    }
    __syncthreads();
  }
}

// ---------------- zero t=0 slice -------------------------------------------------
__global__ __launch_bounds__(256) void k_zero0(float* __restrict__ outp) {
  outp[(size_t)blockIdx.x * (TLEN * 256) + threadIdx.x] = 0.f;
}

extern "C" void kernel_launch(void* const* d_in, const int* in_sizes, int n_in,
                              void* d_out, int out_size, void* d_ws, size_t ws_size,
                              hipStream_t stream) {
  (void)in_sizes; (void)n_in; (void)out_size; (void)ws_size;
  const int* src = (const int*)d_in[0];
  const int* trg = (const int*)d_in[1];
  const float* enc_emb = (const float*)d_in[2];
  const float* eWih_f = (const float*)d_in[3];
  const float* eWhh_f = (const float*)d_in[4];
  const float* ebih_f = (const float*)d_in[5];
  const float* ebhh_f = (const float*)d_in[6];
  const float* eWih_b = (const float*)d_in[7];
  const float* eWhh_b = (const float*)d_in[8];
  const float* ebih_b = (const float*)d_in[9];
  const float* ebhh_b = (const float*)d_in[10];
  const float* Wproj = (const float*)d_in[11];
  const float* bproj = (const float*)d_in[12];
  const float* dec_emb = (const float*)d_in[13];
  const float* Wattn = (const float*)d_in[14];
  const float* battn = (const float*)d_in[15];
  const float* v_attn = (const float*)d_in[16];
  const float* dWih = (const float*)d_in[17];
  const float* dWhh = (const float*)d_in[18];
  const float* dbih = (const float*)d_in[19];
  const float* dbhh = (const float*)d_in[20];
  const float* Wfc = (const float*)d_in[21];
  const float* bfc = (const float*)d_in[22];
  float* dout = (float*)d_out;

  char* base = (char*)d_ws;
  size_t off = 0;
  auto alloc = [&](size_t bytes) {
    void* p = base + off;
    off += (bytes + 255) & ~(size_t)255;
    return p;
  };
  u16* enc_b     = (u16*)alloc((size_t)BSZ * SLEN * 512 * 2);
  u16* enc_pre_b = (u16*)alloc((size_t)BSZ * SLEN * 256 * 2);
  u16* bcat      = (u16*)alloc((size_t)31 * BSZ * 768 * 2);
  float* gi_t    = (float*)alloc((size_t)31 * BSZ * 768 * 4);
  float* tabf    = (float*)alloc((size_t)64 * 768 * 4);
  float* tabb    = (float*)alloc((size_t)64 * 768 * 4);
  float* tabd    = (float*)alloc((size_t)256 * 768 * 4);
  u16* hcatB     = (u16*)alloc((size_t)BSZ * 512 * 2);
  float* h0f     = (float*)alloc((size_t)BSZ * 256 * 4);
  u16* Whhf_b    = (u16*)alloc((size_t)768 * 256 * 2);
  u16* Whhb_b    = (u16*)alloc((size_t)768 * 256 * 2);
  u16* We_b      = (u16*)alloc((size_t)256 * 512 * 2);
  u16* Wd_b      = (u16*)alloc((size_t)256 * 256 * 2);
  u16* Wproj_b   = (u16*)alloc((size_t)256 * 512 * 2);
  u16* Wg_lo     = (u16*)alloc((size_t)768 * 512 * 2);
  u16* Wg_hi     = (u16*)alloc((size_t)768 * 256 * 2);
  u16* Wfc_b     = (u16*)alloc((size_t)256 * 768 * 2);

  // tables + weight packs
  k_gi_table<<<dim3(64, 3), 256, 0, stream>>>(enc_emb, eWih_f, EDIM, ebih_f, tabf);
  k_gi_table<<<dim3(64, 3), 256, 0, stream>>>(enc_emb, eWih_b, EDIM, ebih_b, tabb);
  k_gi_table<<<dim3(256, 3), 256, 0, stream>>>(dec_emb, dWih, 640, dbih, tabd);
  k_gather<<<dim3(TLEN - 1, BSZ), 256, 0, stream>>>(tabd, trg, gi_t);
  k_pack<<<dim3(768), 256, 0, stream>>>(Whhf_b, eWhh_f, 256, 0, 256);
  k_pack<<<dim3(768), 256, 0, stream>>>(Whhb_b, eWhh_b, 256, 0, 256);
  k_pack<<<dim3(256), 256, 0, stream>>>(We_b, Wattn, 768, 256, 512);
  k_pack<<<dim3(256), 256, 0, stream>>>(Wd_b, Wattn, 768, 0, 256);
  k_pack<<<dim3(256), 256, 0, stream>>>(Wproj_b, Wproj, 512, 0, 512);
  k_pack<<<dim3(768), 256, 0, stream>>>(Wg_lo, dWih, 640, 128, 512);
  k_pack<<<dim3(768), 256, 0, stream>>>(Wg_hi, dWhh, 256, 0, 256);
  k_pack<<<dim3(256), 256, 0, stream>>>(Wfc_b, Wfc, 768, 0, 768);

  // encoder: persistent, 256 blocks x 4 rows
  {
    EncArgs ea{enc_b, hcatB, src, Whhf_b, Whhb_b, ebhh_f, ebhh_b, tabf, tabb};
    k_enc_p<<<dim3(256), dim3(1024), 0, stream>>>(ea);
  }

  // hdec = hcat @ Wproj^T + bproj (fp32 out)
  k_bgemm<false><<<dim3(8, 4), 256, 0, stream>>>(hcatB, 512, Wproj_b, 512, bproj, h0f, 256, 512);
  // enc_pre (bf16) = enc_b @ We^T + battn
  k_bgemm<true><<<dim3(256, 4), 256, 0, stream>>>(enc_b, 512, We_b, 512, battn,
                                                  enc_pre_b, 256, 512);
  k_zero0<<<dim3(BSZ), 256, 0, stream>>>(dout);

  // decoder: persistent, 256 blocks x 4 rows, 4 barriers/step
  {
    DecArgs da{enc_b, enc_pre_b, v_attn, Wd_b, Wg_lo, Wg_hi, dbhh, gi_t, h0f, bcat};
    k_dec_p<<<dim3(256), dim3(1024), 0, stream>>>(da);
  }

  // deferred logits: [hn|ctx] @ Wfc^T + bfc for all 31 steps at once
  k_bgemm_logits<<<dim3(248, 4), 256, 0, stream>>>(bcat, Wfc_b, bfc, dout);
}

// Round 15
// 2397.868 us; speedup vs baseline: 2.0803x; 1.0083x over previous
//
#include <hip/hip_runtime.h>
#include <math.h>

#define BSZ 1024
#define SLEN 32
#define TLEN 32
#define EDIM 128
#define HLD 266
#define HFLD 260

typedef unsigned short u16;
typedef __attribute__((ext_vector_type(8))) short bf16x8;
typedef __attribute__((ext_vector_type(4))) float f32x4;

__device__ __forceinline__ float sgm(float x) { return 1.0f / (1.0f + __expf(-x)); }
__device__ __forceinline__ float tanh_fast(float x) {
  float e = __expf(-2.0f * fabsf(x));
  float t = (1.0f - e) / (1.0f + e);
  return copysignf(t, x);
}
__device__ __forceinline__ u16 f2b(float f) {
  union { float f; unsigned u; } v; v.f = f;
  unsigned r = v.u + 0x7fffu + ((v.u >> 16) & 1u);
  return (u16)(r >> 16);
}
__device__ __forceinline__ float b2f(u16 h) {
  union { unsigned u; float f; } v; v.u = ((unsigned)h) << 16; return v.f;
}
__device__ __forceinline__ void unpk(unsigned p, float& x, float& y) {
  union { unsigned u; float f; } a, b;
  a.u = p << 16; b.u = p & 0xffff0000u;
  x = a.f; y = b.f;
}

typedef __attribute__((address_space(1))) const void gv_t;
typedef __attribute__((address_space(3))) void lv_t;
__device__ __forceinline__ void gload16(const void* g, void* l) {
  __builtin_amdgcn_global_load_lds((gv_t*)g, (lv_t*)l, 16, 0, 0);
}

// ---------------- gi tables -------------------------------------------------------
__global__ __launch_bounds__(256) void k_gi_table(const float* __restrict__ emb,
                                                  const float* __restrict__ Wih, int ldw,
                                                  const float* __restrict__ bih,
                                                  float* __restrict__ tab) {
  int v = blockIdx.x;
  int g = blockIdx.y * 256 + threadIdx.x;
  __shared__ float e[EDIM];
  if (threadIdx.x < EDIM) e[threadIdx.x] = emb[v * EDIM + threadIdx.x];
  __syncthreads();
  const float4* w4 = (const float4*)(Wih + (size_t)g * ldw);
  float acc = 0.f;
#pragma unroll
  for (int j = 0; j < EDIM / 4; ++j) {
    float4 w = w4[j];
    acc += w.x * e[4 * j] + w.y * e[4 * j + 1] + w.z * e[4 * j + 2] + w.w * e[4 * j + 3];
  }
  tab[(size_t)v * 768 + g] = acc + bih[g];
}

// ---------------- gi pre-gather ---------------------------------------------------
__global__ __launch_bounds__(256) void k_gather(const float* __restrict__ tabd,
                                                const int* __restrict__ trg,
                                                float* __restrict__ gi) {
  int t = blockIdx.x, b = blockIdx.y;
  int tok = trg[(size_t)b * TLEN + t];
  const float* src = tabd + (size_t)tok * 768;
  float* dst = gi + ((size_t)t * BSZ + b) * 768;
  for (int g = threadIdx.x; g < 768; g += 256) dst[g] = src[g];
}

// ---------------- fp32 -> bf16 weight pack ---------------------------------------
__global__ __launch_bounds__(256) void k_pack(u16* __restrict__ dst,
                                              const float* __restrict__ src, int ld,
                                              int off, int n) {
  int r = blockIdx.x;
  for (int c = threadIdx.x; c < n; c += 256)
    dst[(size_t)r * n + c] = f2b(src[(size_t)r * ld + off + c]);
}

// gates B matrix (1024 x 768): rows 0-511 = [dWih_ctx | dWhh] (R,Z);
// rows 512-767 = [dWih_ctx_n | 0]; rows 768-1023 = [0 | dWhh_n]
__global__ __launch_bounds__(256) void k_pack_gates(u16* __restrict__ Wg,
                                                    const float* __restrict__ dWih,
                                                    const float* __restrict__ dWhh) {
  int r = blockIdx.x;
  for (int c = threadIdx.x; c < 768; c += 256) {
    float v;
    if (r < 512)      v = (c < 512) ? dWih[(size_t)r * 640 + 128 + c] : dWhh[(size_t)r * 256 + (c - 512)];
    else if (r < 768) v = (c < 512) ? dWih[(size_t)r * 640 + 128 + c] : 0.f;
    else              v = (c < 512) ? 0.f : dWhh[(size_t)(r - 256) * 256 + (c - 512)];
    Wg[(size_t)r * 768 + c] = f2b(v);
  }
}

// ---------------- bf16 MFMA GEMM 128x64: out = A.B^T + bias ----------------------
template <bool B16OUT>
__global__ __launch_bounds__(256) void k_bgemm(const u16* __restrict__ A, int lda,
                                               const u16* __restrict__ B, int ldb,
                                               const float* __restrict__ bias,
                                               void* __restrict__ outv, int ldo, int K) {
  __shared__ u16 sA[128 * 64];
  __shared__ u16 sB[64 * 64];
  int m0 = blockIdx.x * 128, n0 = blockIdx.y * 64;
  int tid = threadIdx.x, w = tid >> 6, l = tid & 63;
  int wr = w >> 1, wc = w & 1;
  f32x4 acc[4][2] = {};
  for (int k0 = 0; k0 < K; k0 += 64) {
    __syncthreads();
#pragma unroll
    for (int i = 0; i < 4; ++i) {
      int chunk = i * 4 + w;
      int d = chunk * 1024 + l * 16;
      int lg = d ^ (((d >> 7) & 7) << 4);
      int row = lg >> 7, kb = lg & 127;
      gload16((const char*)(A + (size_t)(m0 + row) * lda + k0) + kb, (char*)sA + chunk * 1024);
    }
#pragma unroll
    for (int i = 0; i < 2; ++i) {
      int chunk = i * 4 + w;
      int d = chunk * 1024 + l * 16;
      int lg = d ^ (((d >> 7) & 7) << 4);
      int row = lg >> 7, kb = lg & 127;
      gload16((const char*)(B + (size_t)(n0 + row) * ldb + k0) + kb, (char*)sB + chunk * 1024);
    }
    __syncthreads();
#pragma unroll
    for (int kk = 0; kk < 2; ++kk) {
      bf16x8 av[4], bv[2];
#pragma unroll
      for (int fm = 0; fm < 4; ++fm) {
        int row = wr * 64 + fm * 16 + (l & 15);
        int addr = (row * 128 + kk * 64 + (l >> 4) * 16) ^ ((row & 7) << 4);
        av[fm] = *(const bf16x8*)((const char*)sA + addr);
      }
#pragma unroll
      for (int fn = 0; fn < 2; ++fn) {
        int row = wc * 32 + fn * 16 + (l & 15);
        int addr = (row * 128 + kk * 64 + (l >> 4) * 16) ^ ((row & 7) << 4);
        bv[fn] = *(const bf16x8*)((const char*)sB + addr);
      }
#pragma unroll
      for (int fm = 0; fm < 4; ++fm)
#pragma unroll
        for (int fn = 0; fn < 2; ++fn)
          acc[fm][fn] = __builtin_amdgcn_mfma_f32_16x16x32_bf16(av[fm], bv[fn], acc[fm][fn], 0, 0, 0);
    }
  }
#pragma unroll
  for (int fn = 0; fn < 2; ++fn) {
    int c = n0 + wc * 32 + fn * 16 + (l & 15);
    float bb = bias ? bias[c] : 0.f;
#pragma unroll
    for (int fm = 0; fm < 4; ++fm) {
      int r = m0 + wr * 64 + fm * 16 + (l >> 4) * 4;
#pragma unroll
      for (int j = 0; j < 4; ++j) {
        float val = acc[fm][fn][j] + bb;
        if (B16OUT) ((u16*)outv)[(size_t)(r + j) * ldo + c] = f2b(val);
        else        ((float*)outv)[(size_t)(r + j) * ldo + c] = val;
      }
    }
  }
}

// ---------------- batched logits GEMM: bcat(31744x768) @ Wfc^T -> dout scatter ----
__global__ __launch_bounds__(256) void k_bgemm_logits(const u16* __restrict__ A,
                                                      const u16* __restrict__ B,
                                                      const float* __restrict__ bias,
                                                      float* __restrict__ dout) {
  __shared__ u16 sA[128 * 64];
  __shared__ u16 sB[64 * 64];
  int m0 = blockIdx.x * 128, n0 = blockIdx.y * 64;
  int tid = threadIdx.x, w = tid >> 6, l = tid & 63;
  int wr = w >> 1, wc = w & 1;
  f32x4 acc[4][2] = {};
  for (int k0 = 0; k0 < 768; k0 += 64) {
    __syncthreads();
#pragma unroll
    for (int i = 0; i < 4; ++i) {
      int chunk = i * 4 + w;
      int d = chunk * 1024 + l * 16;
      int lg = d ^ (((d >> 7) & 7) << 4);
      int row = lg >> 7, kb = lg & 127;
      gload16((const char*)(A + (size_t)(m0 + row) * 768 + k0) + kb, (char*)sA + chunk * 1024);
    }
#pragma unroll
    for (int i = 0; i < 2; ++i) {
      int chunk = i * 4 + w;
      int d = chunk * 1024 + l * 16;
      int lg = d ^ (((d >> 7) & 7) << 4);
      int row = lg >> 7, kb = lg & 127;
      gload16((const char*)(B + (size_t)(n0 + row) * 768 + k0) + kb, (char*)sB + chunk * 1024);
    }
    __syncthreads();
#pragma unroll
    for (int kk = 0; kk < 2; ++kk) {
      bf16x8 av[4], bv[2];
#pragma unroll
      for (int fm = 0; fm < 4; ++fm) {
        int row = wr * 64 + fm * 16 + (l & 15);
        int addr = (row * 128 + kk * 64 + (l >> 4) * 16) ^ ((row & 7) << 4);
        av[fm] = *(const bf16x8*)((const char*)sA + addr);
      }
#pragma unroll
      for (int fn = 0; fn < 2; ++fn) {
        int row = wc * 32 + fn * 16 + (l & 15);
        int addr = (row * 128 + kk * 64 + (l >> 4) * 16) ^ ((row & 7) << 4);
        bv[fn] = *(const bf16x8*)((const char*)sB + addr);
      }
#pragma unroll
      for (int fm = 0; fm < 4; ++fm)
#pragma unroll
        for (int fn = 0; fn < 2; ++fn)
          acc[fm][fn] = __builtin_amdgcn_mfma_f32_16x16x32_bf16(av[fm], bv[fn], acc[fm][fn], 0, 0, 0);
    }
  }
#pragma unroll
  for (int fn = 0; fn < 2; ++fn) {
    int c = n0 + wc * 32 + fn * 16 + (l & 15);
    float bb = bias[c];
#pragma unroll
    for (int fm = 0; fm < 4; ++fm) {
#pragma unroll
      for (int j = 0; j < 4; ++j) {
        int gr = m0 + wr * 64 + fm * 16 + (l >> 4) * 4 + j;
        int tt = gr >> 10, b = gr & 1023;
        dout[(size_t)b * (TLEN * 256) + (size_t)(tt + 1) * 256 + c] = acc[fm][fn][j] + bb;
      }
    }
  }
}

// ---------------- persistent encoder: 256 blocks x 4 rows (round-12, proven) -----
struct EncArgs {
  u16* enc_b; u16* hcatB; const int* src;
  const u16* Whhf; const u16* Whhb;
  const float* bhhf; const float* bhhb;
  const float* tabf; const float* tabb;
};

__global__ __launch_bounds__(1024, 4) void k_enc_p(EncArgs E) {
  __shared__ float hF[2][4 * HFLD];
  __shared__ u16 hB[2][16 * HLD];
  __shared__ int toks[128];
  int r0 = blockIdx.x * 4;
  int tid = threadIdx.x, w = tid >> 6, l = tid & 63;
  int dir = w >> 3, wc = w & 7;
  for (int i = tid; i < 16 * HLD; i += 1024) { hB[0][i] = 0; hB[1][i] = 0; }
  __syncthreads();
  if (tid < 1024) {
    int r = tid >> 8, c = tid & 255;
    hF[0][r * HFLD + c] = 0.f; hF[1][r * HFLD + c] = 0.f;
  }
  if (tid < 128) toks[tid] = E.src[(size_t)(r0 + (tid >> 5)) * SLEN + (tid & 31)];
  __syncthreads();
  const u16* Whh = dir ? E.Whhb : E.Whhf;
  const float* tab = dir ? E.tabb : E.tabf;
  const float* bhh = dir ? E.bhhb : E.bhhf;
  for (int s = 0; s < SLEN; ++s) {
    int s_store = dir ? (SLEN - 1 - s) : s;
    f32x4 ae[3][2] = {};
    if (s > 0) {
#pragma unroll
      for (int kk = 0; kk < 8; ++kk) {
        bf16x8 av = *(const bf16x8*)(hB[dir] + (l & 15) * HLD + kk * 32 + (l >> 4) * 8);
#pragma unroll
        for (int g = 0; g < 3; ++g)
#pragma unroll
          for (int fn = 0; fn < 2; ++fn) {
            bf16x8 bv = *(const bf16x8*)(Whh +
                (size_t)(g * 256 + wc * 32 + fn * 16 + (l & 15)) * 256 + kk * 32 + (l >> 4) * 8);
            ae[g][fn] = __builtin_amdgcn_mfma_f32_16x16x32_bf16(av, bv, ae[g][fn], 0, 0, 0);
          }
      }
    }
    __syncthreads();
#pragma unroll
    for (int fn = 0; fn < 2; ++fn) {
      int c = wc * 32 + fn * 16 + (l & 15);
      float bR = bhh[c], bZ = bhh[256 + c], bN = bhh[512 + c];
#pragma unroll
      for (int j = 0; j < 4; ++j) {
        int row = (l >> 4) * 4 + j;
        if (row < 4) {
          const float* tb = tab + (size_t)toks[row * 32 + s_store] * 768 + c;
          float rg = sgm(tb[0] + ae[0][fn][j] + bR);
          float zg = sgm(tb[256] + ae[1][fn][j] + bZ);
          float ng = tanh_fast(tb[512] + rg * (ae[2][fn][j] + bN));
          float hold = hF[dir][row * HFLD + c];
          float hv = (1.f - zg) * ng + zg * hold;
          hF[dir][row * HFLD + c] = hv;
          u16 hb16 = f2b(hv);
          hB[dir][row * HLD + c] = hb16;
          E.enc_b[((size_t)(r0 + row) * SLEN + s_store) * 512 + dir * 256 + c] = hb16;
        }
      }
    }
    __syncthreads();
  }
  for (int i = tid; i < 4 * 512; i += 1024) {
    int r = i >> 9, c = i & 511;
    E.hcatB[(size_t)(r0 + r) * 512 + c] =
        (c < 256) ? hB[0][r * HLD + c] : hB[1][r * HLD + (c - 256)];
  }
}

// ---------------- K1: fused attn for 8 rows/block (round-5 proven pattern) -------
// reads h from cat[.,512:768]; writes ctx to cat[.,0:512] and bcat_t[.,256:768]
__global__ __launch_bounds__(256) void k_attn8(u16* __restrict__ cat,
                                               const u16* __restrict__ enc_pre_b,
                                               const u16* __restrict__ enc_b,
                                               const float* __restrict__ v_attn,
                                               const u16* __restrict__ Wd_b,
                                               u16* __restrict__ bcat_t) {
  __shared__ __align__(16) char smem[9728];
  float* hwS = (float*)smem;           // 8 x 256
  float* vS = (float*)(smem + 8192);   // 256
  float* awS = (float*)(smem + 9216);  // 8 x 32 (uses 1024B)
  int b0 = blockIdx.x * 8;
  int tid = threadIdx.x, w = tid >> 6, l = tid & 63;
  vS[tid] = v_attn[tid];
  // hWd: wave w covers attn cols [64w, 64w+64)
  f32x4 acc[4] = {};
  for (int k0 = 0; k0 < 256; k0 += 32) {
    bf16x8 av = *(const bf16x8*)(cat + (size_t)(b0 + (l & 15)) * 768 + 512 + k0 + (l >> 4) * 8);
#pragma unroll
    for (int fn = 0; fn < 4; ++fn) {
      bf16x8 bv = *(const bf16x8*)(Wd_b + (size_t)(w * 64 + fn * 16 + (l & 15)) * 256 +
                                   k0 + (l >> 4) * 8);
      acc[fn] = __builtin_amdgcn_mfma_f32_16x16x32_bf16(av, bv, acc[fn], 0, 0, 0);
    }
  }
#pragma unroll
  for (int fn = 0; fn < 4; ++fn) {
    int c = w * 64 + fn * 16 + (l & 15);
#pragma unroll
    for (int j = 0; j < 4; ++j) {
      int r = (l >> 4) * 4 + j;
      if (r < 8) hwS[r * 256 + c] = acc[fn][j];
    }
  }
  __syncthreads();
  // scores: thread -> (r = tid>>5, s = tid&31)
  int r = tid >> 5, s = tid & 31;
  const u16* ep = enc_pre_b + ((size_t)(b0 + r) * SLEN + s) * 256;
  float sum = 0.f;
  for (int a0 = 0; a0 < 256; a0 += 8) {
    bf16x8 pk = *(const bf16x8*)(ep + a0);
    float4 h0 = *(const float4*)&hwS[r * 256 + a0];
    float4 h1 = *(const float4*)&hwS[r * 256 + a0 + 4];
    float4 v0 = *(const float4*)&vS[a0];
    float4 v1 = *(const float4*)&vS[a0 + 4];
    sum += v0.x * tanh_fast(b2f((u16)pk[0]) + h0.x) + v0.y * tanh_fast(b2f((u16)pk[1]) + h0.y) +
           v0.z * tanh_fast(b2f((u16)pk[2]) + h0.z) + v0.w * tanh_fast(b2f((u16)pk[3]) + h0.w) +
           v1.x * tanh_fast(b2f((u16)pk[4]) + h1.x) + v1.y * tanh_fast(b2f((u16)pk[5]) + h1.y) +
           v1.z * tanh_fast(b2f((u16)pk[6]) + h1.z) + v1.w * tanh_fast(b2f((u16)pk[7]) + h1.w);
  }
  float m = sum;
#pragma unroll
  for (int o = 16; o >= 1; o >>= 1) m = fmaxf(m, __shfl_xor(m, o, 32));
  float e = __expf(sum - m), ss = e;
#pragma unroll
  for (int o = 16; o >= 1; o >>= 1) ss += __shfl_xor(ss, o, 32);
  awS[r * 32 + s] = e / ss;
  __syncthreads();
  // ctx: thread -> cols [2*tid, 2*tid+2)
  int c = tid * 2;
#pragma unroll
  for (int rr = 0; rr < 8; ++rr) {
    float ax = 0.f, ay = 0.f;
    const u16* eb = enc_b + (size_t)(b0 + rr) * (SLEN * 512) + c;
#pragma unroll 8
    for (int si = 0; si < 32; ++si) {
      float a = awS[rr * 32 + si];
      unsigned pk = *(const unsigned*)(eb + si * 512);
      float x, y; unpk(pk, x, y);
      ax += a * x; ay += a * y;
    }
    unsigned o = (unsigned)f2b(ax) | ((unsigned)f2b(ay) << 16);
    *(unsigned*)(cat + (size_t)(b0 + rr) * 768 + c) = o;
    *(unsigned*)(bcat_t + (size_t)(b0 + rr) * 768 + 256 + c) = o;
  }
}

// ---------------- K2b: GRU epilogue (elementwise) --------------------------------
__global__ __launch_bounds__(256) void k_gru_ep(const float* __restrict__ gbuf,
                                                const float* __restrict__ gi_t,
                                                const float* __restrict__ dbhh,
                                                const float* __restrict__ h_cur,
                                                float* __restrict__ h_nxt,
                                                u16* __restrict__ cat_nxt,
                                                u16* __restrict__ bcat_t) {
  int row = blockIdx.x, c = threadIdx.x;
  const float* g = gbuf + (size_t)row * 1024;
  const float* gi = gi_t + (size_t)row * 768;
  float rg = sgm(gi[c] + g[c] + dbhh[c]);
  float zg = sgm(gi[256 + c] + g[256 + c] + dbhh[256 + c]);
  float ng = tanh_fast(gi[512 + c] + g[512 + c] + rg * (g[768 + c] + dbhh[512 + c]));
  float hold = h_cur[(size_t)row * 256 + c];
  float hv = (1.f - zg) * ng + zg * hold;
  h_nxt[(size_t)row * 256 + c] = hv;
  u16 hb = f2b(hv);
  cat_nxt[(size_t)row * 768 + 512 + c] = hb;
  bcat_t[(size_t)row * 768 + c] = hb;
}

// ---------------- h fp32 -> bf16 into cat[512:768] -------------------------------
__global__ __launch_bounds__(256) void k_h2b(const float* __restrict__ h,
                                             u16* __restrict__ cat) {
  int row = blockIdx.x, c = threadIdx.x;
  cat[(size_t)row * 768 + 512 + c] = f2b(h[(size_t)row * 256 + c]);
}

// ---------------- zero t=0 slice -------------------------------------------------
__global__ __launch_bounds__(256) void k_zero0(float* __restrict__ outp) {
  outp[(size_t)blockIdx.x * (TLEN * 256) + threadIdx.x] = 0.f;
}

extern "C" void kernel_launch(void* const* d_in, const int* in_sizes, int n_in,
                              void* d_out, int out_size, void* d_ws, size_t ws_size,
                              hipStream_t stream) {
  (void)in_sizes; (void)n_in; (void)out_size; (void)ws_size;
  const int* src = (const int*)d_in[0];
  const int* trg = (const int*)d_in[1];
  const float* enc_emb = (const float*)d_in[2];
  const float* eWih_f = (const float*)d_in[3];
  const float* eWhh_f = (const float*)d_in[4];
  const float* ebih_f = (const float*)d_in[5];
  const float* ebhh_f = (const float*)d_in[6];
  const float* eWih_b = (const float*)d_in[7];
  const float* eWhh_b = (const float*)d_in[8];
  const float* ebih_b = (const float*)d_in[9];
  const float* ebhh_b = (const float*)d_in[10];
  const float* Wproj = (const float*)d_in[11];
  const float* bproj = (const float*)d_in[12];
  const float* dec_emb = (const float*)d_in[13];
  const float* Wattn = (const float*)d_in[14];
  const float* battn = (const float*)d_in[15];
  const float* v_attn = (const float*)d_in[16];
  const float* dWih = (const float*)d_in[17];
  const float* dWhh = (const float*)d_in[18];
  const float* dbih = (const float*)d_in[19];
  const float* dbhh = (const float*)d_in[20];
  const float* Wfc = (const float*)d_in[21];
  const float* bfc = (const float*)d_in[22];
  float* dout = (float*)d_out;

  char* base = (char*)d_ws;
  size_t off = 0;
  auto alloc = [&](size_t bytes) {
    void* p = base + off;
    off += (bytes + 255) & ~(size_t)255;
    return p;
  };
  u16* enc_b     = (u16*)alloc((size_t)BSZ * SLEN * 512 * 2);
  u16* enc_pre_b = (u16*)alloc((size_t)BSZ * SLEN * 256 * 2);
  u16* bcat      = (u16*)alloc((size_t)31 * BSZ * 768 * 2);
  float* gi_t    = (float*)alloc((size_t)31 * BSZ * 768 * 4);
  float* gbuf    = (float*)alloc((size_t)BSZ * 1024 * 4);
  float* tabf    = (float*)alloc((size_t)64 * 768 * 4);
  float* tabb    = (float*)alloc((size_t)64 * 768 * 4);
  float* tabd    = (float*)alloc((size_t)256 * 768 * 4);
  u16* hcatB     = (u16*)alloc((size_t)BSZ * 512 * 2);
  float* h0f     = (float*)alloc((size_t)BSZ * 256 * 4);
  float* h1f     = (float*)alloc((size_t)BSZ * 256 * 4);
  u16* Whhf_b    = (u16*)alloc((size_t)768 * 256 * 2);
  u16* Whhb_b    = (u16*)alloc((size_t)768 * 256 * 2);
  u16* We_b      = (u16*)alloc((size_t)256 * 512 * 2);
  u16* Wd_b      = (u16*)alloc((size_t)256 * 256 * 2);
  u16* Wproj_b   = (u16*)alloc((size_t)256 * 512 * 2);
  u16* Wg        = (u16*)alloc((size_t)1024 * 768 * 2);
  u16* Wfc_b     = (u16*)alloc((size_t)256 * 768 * 2);
  u16* cat0      = (u16*)alloc((size_t)BSZ * 768 * 2);
  u16* cat1      = (u16*)alloc((size_t)BSZ * 768 * 2);
  (void)alloc(65536);  // pad: k_attn8 A-fragments over-read past last rows

  // tables + weight packs
  k_gi_table<<<dim3(64, 3), 256, 0, stream>>>(enc_emb, eWih_f, EDIM, ebih_f, tabf);
  k_gi_table<<<dim3(64, 3), 256, 0, stream>>>(enc_emb, eWih_b, EDIM, ebih_b, tabb);
  k_gi_table<<<dim3(256, 3), 256, 0, stream>>>(dec_emb, dWih, 640, dbih, tabd);
  k_gather<<<dim3(TLEN - 1, BSZ), 256, 0, stream>>>(tabd, trg, gi_t);
  k_pack<<<dim3(768), 256, 0, stream>>>(Whhf_b, eWhh_f, 256, 0, 256);
  k_pack<<<dim3(768), 256, 0, stream>>>(Whhb_b, eWhh_b, 256, 0, 256);
  k_pack<<<dim3(256), 256, 0, stream>>>(We_b, Wattn, 768, 256, 512);
  k_pack<<<dim3(256), 256, 0, stream>>>(Wd_b, Wattn, 768, 0, 256);
  k_pack<<<dim3(256), 256, 0, stream>>>(Wproj_b, Wproj, 512, 0, 512);
  k_pack_gates<<<dim3(1024), 256, 0, stream>>>(Wg, dWih, dWhh);
  k_pack<<<dim3(256), 256, 0, stream>>>(Wfc_b, Wfc, 768, 0, 768);

  // encoder: persistent, 256 blocks x 4 rows (round-12 proven)
  {
    EncArgs ea{enc_b, hcatB, src, Whhf_b, Whhb_b, ebhh_f, ebhh_b, tabf, tabb};
    k_enc_p<<<dim3(256), dim3(1024), 0, stream>>>(ea);
  }

  // hdec = hcat @ Wproj^T + bproj (fp32 out), then bf16 into cat0[512:768]
  k_bgemm<false><<<dim3(8, 4), 256, 0, stream>>>(hcatB, 512, Wproj_b, 512, bproj, h0f, 256, 512);
  k_h2b<<<dim3(BSZ), 256, 0, stream>>>(h0f, cat0);

  // enc_pre (bf16) = enc_b @ We^T + battn
  k_bgemm<true><<<dim3(256, 4), 256, 0, stream>>>(enc_b, 512, We_b, 512, battn,
                                                  enc_pre_b, 256, 512);
  k_zero0<<<dim3(BSZ), 256, 0, stream>>>(dout);

  // decoder: 31 steps x 3 small kernels (weights L2-shared via GEMM tiling)
  for (int t = 0; t < TLEN - 1; ++t) {
    u16* cc = (t & 1) ? cat1 : cat0;
    u16* cn = (t & 1) ? cat0 : cat1;
    float* hc = (t & 1) ? h1f : h0f;
    float* hn = (t & 1) ? h0f : h1f;
    u16* bt = bcat + (size_t)t * BSZ * 768;
    k_attn8<<<dim3(128), 256, 0, stream>>>(cc, enc_pre_b, enc_b, v_attn, Wd_b, bt);
    k_bgemm<false><<<dim3(8, 16), 256, 0, stream>>>(cc, 768, Wg, 768, nullptr, gbuf, 1024, 768);
    k_gru_ep<<<dim3(BSZ), 256, 0, stream>>>(gbuf, gi_t + (size_t)t * BSZ * 768, dbhh,
                                            hc, hn, cn, bt);
  }

  // deferred logits: [hn|ctx] @ Wfc^T + bfc for all 31 steps at once
  k_bgemm_logits<<<dim3(248, 4), 256, 0, stream>>>(bcat, Wfc_b, bfc, dout);
}

// Round 16
// 1764.097 us; speedup vs baseline: 2.8277x; 1.3593x over previous
//
#include <hip/hip_runtime.h>
#include <math.h>

#define BSZ 1024
#define SLEN 32
#define TLEN 32
#define EDIM 128
#define HLD 266
#define HFLD 260

typedef unsigned short u16;
typedef __attribute__((ext_vector_type(8))) short bf16x8;
typedef __attribute__((ext_vector_type(4))) float f32x4;

__device__ __forceinline__ float sgm(float x) { return 1.0f / (1.0f + __expf(-x)); }
__device__ __forceinline__ float tanh_fast(float x) {
  float e = __expf(-2.0f * fabsf(x));
  float t = (1.0f - e) / (1.0f + e);
  return copysignf(t, x);
}
__device__ __forceinline__ u16 f2b(float f) {
  union { float f; unsigned u; } v; v.f = f;
  unsigned r = v.u + 0x7fffu + ((v.u >> 16) & 1u);
  return (u16)(r >> 16);
}
__device__ __forceinline__ float b2f(u16 h) {
  union { unsigned u; float f; } v; v.u = ((unsigned)h) << 16; return v.f;
}
__device__ __forceinline__ void unpk(unsigned p, float& x, float& y) {
  union { unsigned u; float f; } a, b;
  a.u = p << 16; b.u = p & 0xffff0000u;
  x = a.f; y = b.f;
}

typedef __attribute__((address_space(1))) const void gv_t;
typedef __attribute__((address_space(3))) void lv_t;
__device__ __forceinline__ void gload16(const void* g, void* l) {
  __builtin_amdgcn_global_load_lds((gv_t*)g, (lv_t*)l, 16, 0, 0);
}

// ---------------- gi tables -------------------------------------------------------
__global__ __launch_bounds__(256) void k_gi_table(const float* __restrict__ emb,
                                                  const float* __restrict__ Wih, int ldw,
                                                  const float* __restrict__ bih,
                                                  float* __restrict__ tab) {
  int v = blockIdx.x;
  int g = blockIdx.y * 256 + threadIdx.x;
  __shared__ float e[EDIM];
  if (threadIdx.x < EDIM) e[threadIdx.x] = emb[v * EDIM + threadIdx.x];
  __syncthreads();
  const float4* w4 = (const float4*)(Wih + (size_t)g * ldw);
  float acc = 0.f;
#pragma unroll
  for (int j = 0; j < EDIM / 4; ++j) {
    float4 w = w4[j];
    acc += w.x * e[4 * j] + w.y * e[4 * j + 1] + w.z * e[4 * j + 2] + w.w * e[4 * j + 3];
  }
  tab[(size_t)v * 768 + g] = acc + bih[g];
}

// ---------------- gi pre-gather ---------------------------------------------------
__global__ __launch_bounds__(256) void k_gather(const float* __restrict__ tabd,
                                                const int* __restrict__ trg,
                                                float* __restrict__ gi) {
  int t = blockIdx.x, b = blockIdx.y;
  int tok = trg[(size_t)b * TLEN + t];
  const float* src = tabd + (size_t)tok * 768;
  float* dst = gi + ((size_t)t * BSZ + b) * 768;
  for (int g = threadIdx.x; g < 768; g += 256) dst[g] = src[g];
}

// ---------------- fp32 -> bf16 weight pack ---------------------------------------
__global__ __launch_bounds__(256) void k_pack(u16* __restrict__ dst,
                                              const float* __restrict__ src, int ld,
                                              int off, int n) {
  int r = blockIdx.x;
  for (int c = threadIdx.x; c < n; c += 256)
    dst[(size_t)r * n + c] = f2b(src[(size_t)r * ld + off + c]);
}

// gates B matrix (1024 x 768)
__global__ __launch_bounds__(256) void k_pack_gates(u16* __restrict__ Wg,
                                                    const float* __restrict__ dWih,
                                                    const float* __restrict__ dWhh) {
  int r = blockIdx.x;
  for (int c = threadIdx.x; c < 768; c += 256) {
    float v;
    if (r < 512)      v = (c < 512) ? dWih[(size_t)r * 640 + 128 + c] : dWhh[(size_t)r * 256 + (c - 512)];
    else if (r < 768) v = (c < 512) ? dWih[(size_t)r * 640 + 128 + c] : 0.f;
    else              v = (c < 512) ? 0.f : dWhh[(size_t)(r - 256) * 256 + (c - 512)];
    Wg[(size_t)r * 768 + c] = f2b(v);
  }
}

// ---------------- bf16 MFMA GEMM 128x64: out = A.B^T + bias ----------------------
template <bool B16OUT>
__global__ __launch_bounds__(256) void k_bgemm(const u16* __restrict__ A, int lda,
                                               const u16* __restrict__ B, int ldb,
                                               const float* __restrict__ bias,
                                               void* __restrict__ outv, int ldo, int K) {
  __shared__ u16 sA[128 * 64];
  __shared__ u16 sB[64 * 64];
  int m0 = blockIdx.x * 128, n0 = blockIdx.y * 64;
  int tid = threadIdx.x, w = tid >> 6, l = tid & 63;
  int wr = w >> 1, wc = w & 1;
  f32x4 acc[4][2] = {};
  for (int k0 = 0; k0 < K; k0 += 64) {
    __syncthreads();
#pragma unroll
    for (int i = 0; i < 4; ++i) {
      int chunk = i * 4 + w;
      int d = chunk * 1024 + l * 16;
      int lg = d ^ (((d >> 7) & 7) << 4);
      int row = lg >> 7, kb = lg & 127;
      gload16((const char*)(A + (size_t)(m0 + row) * lda + k0) + kb, (char*)sA + chunk * 1024);
    }
#pragma unroll
    for (int i = 0; i < 2; ++i) {
      int chunk = i * 4 + w;
      int d = chunk * 1024 + l * 16;
      int lg = d ^ (((d >> 7) & 7) << 4);
      int row = lg >> 7, kb = lg & 127;
      gload16((const char*)(B + (size_t)(n0 + row) * ldb + k0) + kb, (char*)sB + chunk * 1024);
    }
    __syncthreads();
#pragma unroll
    for (int kk = 0; kk < 2; ++kk) {
      bf16x8 av[4], bv[2];
#pragma unroll
      for (int fm = 0; fm < 4; ++fm) {
        int row = wr * 64 + fm * 16 + (l & 15);
        int addr = (row * 128 + kk * 64 + (l >> 4) * 16) ^ ((row & 7) << 4);
        av[fm] = *(const bf16x8*)((const char*)sA + addr);
      }
#pragma unroll
      for (int fn = 0; fn < 2; ++fn) {
        int row = wc * 32 + fn * 16 + (l & 15);
        int addr = (row * 128 + kk * 64 + (l >> 4) * 16) ^ ((row & 7) << 4);
        bv[fn] = *(const bf16x8*)((const char*)sB + addr);
      }
#pragma unroll
      for (int fm = 0; fm < 4; ++fm)
#pragma unroll
        for (int fn = 0; fn < 2; ++fn)
          acc[fm][fn] = __builtin_amdgcn_mfma_f32_16x16x32_bf16(av[fm], bv[fn], acc[fm][fn], 0, 0, 0);
    }
  }
#pragma unroll
  for (int fn = 0; fn < 2; ++fn) {
    int c = n0 + wc * 32 + fn * 16 + (l & 15);
    float bb = bias ? bias[c] : 0.f;
#pragma unroll
    for (int fm = 0; fm < 4; ++fm) {
      int r = m0 + wr * 64 + fm * 16 + (l >> 4) * 4;
#pragma unroll
      for (int j = 0; j < 4; ++j) {
        float val = acc[fm][fn][j] + bb;
        if (B16OUT) ((u16*)outv)[(size_t)(r + j) * ldo + c] = f2b(val);
        else        ((float*)outv)[(size_t)(r + j) * ldo + c] = val;
      }
    }
  }
}

// ---------------- batched logits GEMM: bcat(31744x768) @ Wfc^T -> dout scatter ----
__global__ __launch_bounds__(256) void k_bgemm_logits(const u16* __restrict__ A,
                                                      const u16* __restrict__ B,
                                                      const float* __restrict__ bias,
                                                      float* __restrict__ dout) {
  __shared__ u16 sA[128 * 64];
  __shared__ u16 sB[64 * 64];
  int m0 = blockIdx.x * 128, n0 = blockIdx.y * 64;
  int tid = threadIdx.x, w = tid >> 6, l = tid & 63;
  int wr = w >> 1, wc = w & 1;
  f32x4 acc[4][2] = {};
  for (int k0 = 0; k0 < 768; k0 += 64) {
    __syncthreads();
#pragma unroll
    for (int i = 0; i < 4; ++i) {
      int chunk = i * 4 + w;
      int d = chunk * 1024 + l * 16;
      int lg = d ^ (((d >> 7) & 7) << 4);
      int row = lg >> 7, kb = lg & 127;
      gload16((const char*)(A + (size_t)(m0 + row) * 768 + k0) + kb, (char*)sA + chunk * 1024);
    }
#pragma unroll
    for (int i = 0; i < 2; ++i) {
      int chunk = i * 4 + w;
      int d = chunk * 1024 + l * 16;
      int lg = d ^ (((d >> 7) & 7) << 4);
      int row = lg >> 7, kb = lg & 127;
      gload16((const char*)(B + (size_t)(n0 + row) * 768 + k0) + kb, (char*)sB + chunk * 1024);
    }
    __syncthreads();
#pragma unroll
    for (int kk = 0; kk < 2; ++kk) {
      bf16x8 av[4], bv[2];
#pragma unroll
      for (int fm = 0; fm < 4; ++fm) {
        int row = wr * 64 + fm * 16 + (l & 15);
        int addr = (row * 128 + kk * 64 + (l >> 4) * 16) ^ ((row & 7) << 4);
        av[fm] = *(const bf16x8*)((const char*)sA + addr);
      }
#pragma unroll
      for (int fn = 0; fn < 2; ++fn) {
        int row = wc * 32 + fn * 16 + (l & 15);
        int addr = (row * 128 + kk * 64 + (l >> 4) * 16) ^ ((row & 7) << 4);
        bv[fn] = *(const bf16x8*)((const char*)sB + addr);
      }
#pragma unroll
      for (int fm = 0; fm < 4; ++fm)
#pragma unroll
        for (int fn = 0; fn < 2; ++fn)
          acc[fm][fn] = __builtin_amdgcn_mfma_f32_16x16x32_bf16(av[fm], bv[fn], acc[fm][fn], 0, 0, 0);
    }
  }
#pragma unroll
  for (int fn = 0; fn < 2; ++fn) {
    int c = n0 + wc * 32 + fn * 16 + (l & 15);
    float bb = bias[c];
#pragma unroll
    for (int fm = 0; fm < 4; ++fm) {
#pragma unroll
      for (int j = 0; j < 4; ++j) {
        int gr = m0 + wr * 64 + fm * 16 + (l >> 4) * 4 + j;
        int tt = gr >> 10, b = gr & 1023;
        dout[(size_t)b * (TLEN * 256) + (size_t)(tt + 1) * 256 + c] = acc[fm][fn][j] + bb;
      }
    }
  }
}

// ---------------- encoder v3: 256 blocks = 128 rowgrps x 2 dirs, 8 rows ----------
// Wave w owns hidden cols [w*16, w*16+16) x 3 gates; weights live in 96 VGPRs,
// preloaded once. Step loop: 8 ds_read + 24 MFMA + epilogue; no global weight loads.
struct EncArgs {
  u16* enc_b; u16* hcatB; const int* src;
  const u16* Whhf; const u16* Whhb;
  const float* bhhf; const float* bhhb;
  const float* tabf; const float* tabb;
};

__global__ __launch_bounds__(1024, 4) void k_enc_p(EncArgs E) {
  __shared__ float hF[8 * HFLD];
  __shared__ u16 hB[16 * HLD];  // rows 8-15 stay zero (A-frag over-read)
  __shared__ int toks[256];
  int dir = blockIdx.x & 1;
  int r0 = (blockIdx.x >> 1) * 8;
  int tid = threadIdx.x, w = tid >> 6, l = tid & 63;
  const u16* Whh = dir ? E.Whhb : E.Whhf;
  const float* tab = dir ? E.tabb : E.tabf;
  const float* bhh = dir ? E.bhhb : E.bhhf;
  // preload weights into registers (compile-time indexed -> VGPRs)
  bf16x8 wreg[8][3];
#pragma unroll
  for (int kk = 0; kk < 8; ++kk)
#pragma unroll
    for (int g = 0; g < 3; ++g)
      wreg[kk][g] = *(const bf16x8*)(Whh +
          (size_t)(g * 256 + w * 16 + (l & 15)) * 256 + kk * 32 + (l >> 4) * 8);
  for (int i = tid; i < 16 * HLD; i += 1024) hB[i] = 0;
  for (int i = tid; i < 8 * HFLD; i += 1024) hF[i] = 0.f;
  if (tid < 256) toks[tid] = E.src[(size_t)(r0 + (tid >> 5)) * SLEN + (tid & 31)];
  __syncthreads();
  for (int s = 0; s < SLEN; ++s) {
    int s_store = dir ? (SLEN - 1 - s) : s;
    f32x4 ae[3] = {};
    if (s > 0) {
#pragma unroll
      for (int kk = 0; kk < 8; ++kk) {
        bf16x8 av = *(const bf16x8*)(hB + (l & 15) * HLD + kk * 32 + (l >> 4) * 8);
#pragma unroll
        for (int g = 0; g < 3; ++g)
          ae[g] = __builtin_amdgcn_mfma_f32_16x16x32_bf16(av, wreg[kk][g], ae[g], 0, 0, 0);
      }
    }
    __syncthreads();
    int c = w * 16 + (l & 15);
    float bR = bhh[c], bZ = bhh[256 + c], bN = bhh[512 + c];
#pragma unroll
    for (int j = 0; j < 4; ++j) {
      int row = (l >> 4) * 4 + j;
      if (row < 8) {
        const float* tb = tab + (size_t)toks[row * 32 + s_store] * 768 + c;
        float rg = sgm(tb[0] + ae[0][j] + bR);
        float zg = sgm(tb[256] + ae[1][j] + bZ);
        float ng = tanh_fast(tb[512] + rg * (ae[2][j] + bN));
        float hold = hF[row * HFLD + c];
        float hv = (1.f - zg) * ng + zg * hold;
        hF[row * HFLD + c] = hv;
        u16 hb16 = f2b(hv);
        hB[row * HLD + c] = hb16;
        E.enc_b[((size_t)(r0 + row) * SLEN + s_store) * 512 + dir * 256 + c] = hb16;
      }
    }
    __syncthreads();
  }
  // final h of this dir -> hcat half
  for (int i = tid; i < 8 * 256; i += 1024) {
    int row = i >> 8, c = i & 255;
    E.hcatB[(size_t)(r0 + row) * 512 + dir * 256 + c] = hB[row * HLD + c];
  }
}

// ---------------- K1: attn8 with fused GRU-epilogue prologue ---------------------
__global__ __launch_bounds__(256) void k_attn8_ep(u16* __restrict__ cat,
                                                  const u16* __restrict__ enc_pre_b,
                                                  const u16* __restrict__ enc_b,
                                                  const float* __restrict__ v_attn,
                                                  const u16* __restrict__ Wd_b,
                                                  u16* __restrict__ bcat_t,
                                                  const float* __restrict__ gbuf,
                                                  const float* __restrict__ gi_prev,
                                                  const float* __restrict__ dbhh,
                                                  const float* __restrict__ h_cur,
                                                  float* __restrict__ h_nxt,
                                                  u16* __restrict__ bcat_prev,
                                                  int do_ep) {
  __shared__ __align__(16) char smem[10240];
  float* hwS = (float*)smem;           // 8 x 256
  float* vS = (float*)(smem + 8192);   // 256
  float* awS = (float*)(smem + 9216);  // 8 x 32
  int b0 = blockIdx.x * 8;
  int tid = threadIdx.x, w = tid >> 6, l = tid & 63;
  vS[tid] = v_attn[tid];
  if (do_ep) {
    // GRU epilogue of the previous step: compute h(t) for rows b0..b0+7
    int row = b0 + (tid >> 5);
    int c0 = (tid & 31) * 8;
    const float* g = gbuf + (size_t)row * 1024;
    const float* gi = gi_prev + (size_t)(row) * 768;
#pragma unroll
    for (int q = 0; q < 8; ++q) {
      int c = c0 + q;
      float rg = sgm(gi[c] + g[c] + dbhh[c]);
      float zg = sgm(gi[256 + c] + g[256 + c] + dbhh[256 + c]);
      float ng = tanh_fast(gi[512 + c] + g[512 + c] + rg * (g[768 + c] + dbhh[512 + c]));
      float hold = h_cur[(size_t)row * 256 + c];
      float hv = (1.f - zg) * ng + zg * hold;
      h_nxt[(size_t)row * 256 + c] = hv;
      u16 hb = f2b(hv);
      cat[(size_t)row * 768 + 512 + c] = hb;
      bcat_prev[(size_t)row * 768 + c] = hb;
    }
  }
  __syncthreads();
  // hWd: wave w covers attn cols [64w, 64w+64)
  f32x4 acc[4] = {};
  for (int k0 = 0; k0 < 256; k0 += 32) {
    bf16x8 av = *(const bf16x8*)(cat + (size_t)(b0 + (l & 15)) * 768 + 512 + k0 + (l >> 4) * 8);
#pragma unroll
    for (int fn = 0; fn < 4; ++fn) {
      bf16x8 bv = *(const bf16x8*)(Wd_b + (size_t)(w * 64 + fn * 16 + (l & 15)) * 256 +
                                   k0 + (l >> 4) * 8);
      acc[fn] = __builtin_amdgcn_mfma_f32_16x16x32_bf16(av, bv, acc[fn], 0, 0, 0);
    }
  }
#pragma unroll
  for (int fn = 0; fn < 4; ++fn) {
    int c = w * 64 + fn * 16 + (l & 15);
#pragma unroll
    for (int j = 0; j < 4; ++j) {
      int r = (l >> 4) * 4 + j;
      if (r < 8) hwS[r * 256 + c] = acc[fn][j];
    }
  }
  __syncthreads();
  // scores: thread -> (r = tid>>5, s = tid&31)
  int r = tid >> 5, s = tid & 31;
  const u16* ep = enc_pre_b + ((size_t)(b0 + r) * SLEN + s) * 256;
  float sum = 0.f;
  for (int a0 = 0; a0 < 256; a0 += 8) {
    bf16x8 pk = *(const bf16x8*)(ep + a0);
    float4 h0 = *(const float4*)&hwS[r * 256 + a0];
    float4 h1 = *(const float4*)&hwS[r * 256 + a0 + 4];
    float4 v0 = *(const float4*)&vS[a0];
    float4 v1 = *(const float4*)&vS[a0 + 4];
    sum += v0.x * tanh_fast(b2f((u16)pk[0]) + h0.x) + v0.y * tanh_fast(b2f((u16)pk[1]) + h0.y) +
           v0.z * tanh_fast(b2f((u16)pk[2]) + h0.z) + v0.w * tanh_fast(b2f((u16)pk[3]) + h0.w) +
           v1.x * tanh_fast(b2f((u16)pk[4]) + h1.x) + v1.y * tanh_fast(b2f((u16)pk[5]) + h1.y) +
           v1.z * tanh_fast(b2f((u16)pk[6]) + h1.z) + v1.w * tanh_fast(b2f((u16)pk[7]) + h1.w);
  }
  float m = sum;
#pragma unroll
  for (int o = 16; o >= 1; o >>= 1) m = fmaxf(m, __shfl_xor(m, o, 32));
  float e = __expf(sum - m), ss = e;
#pragma unroll
  for (int o = 16; o >= 1; o >>= 1) ss += __shfl_xor(ss, o, 32);
  awS[r * 32 + s] = e / ss;
  __syncthreads();
  // ctx: thread -> cols [2*tid, 2*tid+2)
  int c = tid * 2;
#pragma unroll
  for (int rr = 0; rr < 8; ++rr) {
    float ax = 0.f, ay = 0.f;
    const u16* eb = enc_b + (size_t)(b0 + rr) * (SLEN * 512) + c;
#pragma unroll 8
    for (int si = 0; si < 32; ++si) {
      float a = awS[rr * 32 + si];
      unsigned pk = *(const unsigned*)(eb + si * 512);
      float x, y; unpk(pk, x, y);
      ax += a * x; ay += a * y;
    }
    unsigned o = (unsigned)f2b(ax) | ((unsigned)f2b(ay) << 16);
    *(unsigned*)(cat + (size_t)(b0 + rr) * 768 + c) = o;
    *(unsigned*)(bcat_t + (size_t)(b0 + rr) * 768 + 256 + c) = o;
  }
}

// ---------------- final GRU epilogue (t=30) --------------------------------------
__global__ __launch_bounds__(256) void k_gru_ep(const float* __restrict__ gbuf,
                                                const float* __restrict__ gi_t,
                                                const float* __restrict__ dbhh,
                                                const float* __restrict__ h_cur,
                                                float* __restrict__ h_nxt,
                                                u16* __restrict__ bcat_t) {
  int row = blockIdx.x, c = threadIdx.x;
  const float* g = gbuf + (size_t)row * 1024;
  const float* gi = gi_t + (size_t)row * 768;
  float rg = sgm(gi[c] + g[c] + dbhh[c]);
  float zg = sgm(gi[256 + c] + g[256 + c] + dbhh[256 + c]);
  float ng = tanh_fast(gi[512 + c] + g[512 + c] + rg * (g[768 + c] + dbhh[512 + c]));
  float hold = h_cur[(size_t)row * 256 + c];
  float hv = (1.f - zg) * ng + zg * hold;
  h_nxt[(size_t)row * 256 + c] = hv;
  bcat_t[(size_t)row * 768 + c] = f2b(hv);
}

// ---------------- h fp32 -> bf16 into cat[512:768] -------------------------------
__global__ __launch_bounds__(256) void k_h2b(const float* __restrict__ h,
                                             u16* __restrict__ cat) {
  int row = blockIdx.x, c = threadIdx.x;
  cat[(size_t)row * 768 + 512 + c] = f2b(h[(size_t)row * 256 + c]);
}

// ---------------- zero t=0 slice -------------------------------------------------
__global__ __launch_bounds__(256) void k_zero0(float* __restrict__ outp) {
  outp[(size_t)blockIdx.x * (TLEN * 256) + threadIdx.x] = 0.f;
}

extern "C" void kernel_launch(void* const* d_in, const int* in_sizes, int n_in,
                              void* d_out, int out_size, void* d_ws, size_t ws_size,
                              hipStream_t stream) {
  (void)in_sizes; (void)n_in; (void)out_size; (void)ws_size;
  const int* src = (const int*)d_in[0];
  const int* trg = (const int*)d_in[1];
  const float* enc_emb = (const float*)d_in[2];
  const float* eWih_f = (const float*)d_in[3];
  const float* eWhh_f = (const float*)d_in[4];
  const float* ebih_f = (const float*)d_in[5];
  const float* ebhh_f = (const float*)d_in[6];
  const float* eWih_b = (const float*)d_in[7];
  const float* eWhh_b = (const float*)d_in[8];
  const float* ebih_b = (const float*)d_in[9];
  const float* ebhh_b = (const float*)d_in[10];
  const float* Wproj = (const float*)d_in[11];
  const float* bproj = (const float*)d_in[12];
  const float* dec_emb = (const float*)d_in[13];
  const float* Wattn = (const float*)d_in[14];
  const float* battn = (const float*)d_in[15];
  const float* v_attn = (const float*)d_in[16];
  const float* dWih = (const float*)d_in[17];
  const float* dWhh = (const float*)d_in[18];
  const float* dbih = (const float*)d_in[19];
  const float* dbhh = (const float*)d_in[20];
  const float* Wfc = (const float*)d_in[21];
  const float* bfc = (const float*)d_in[22];
  float* dout = (float*)d_out;

  char* base = (char*)d_ws;
  size_t off = 0;
  auto alloc = [&](size_t bytes) {
    void* p = base + off;
    off += (bytes + 255) & ~(size_t)255;
    return p;
  };
  u16* enc_b     = (u16*)alloc((size_t)BSZ * SLEN * 512 * 2);
  u16* enc_pre_b = (u16*)alloc((size_t)BSZ * SLEN * 256 * 2);
  u16* bcat      = (u16*)alloc((size_t)31 * BSZ * 768 * 2);
  float* gi_t    = (float*)alloc((size_t)31 * BSZ * 768 * 4);
  float* gbuf    = (float*)alloc((size_t)BSZ * 1024 * 4);
  float* tabf    = (float*)alloc((size_t)64 * 768 * 4);
  float* tabb    = (float*)alloc((size_t)64 * 768 * 4);
  float* tabd    = (float*)alloc((size_t)256 * 768 * 4);
  u16* hcatB     = (u16*)alloc((size_t)BSZ * 512 * 2);
  float* h0f     = (float*)alloc((size_t)BSZ * 256 * 4);
  float* h1f     = (float*)alloc((size_t)BSZ * 256 * 4);
  u16* Whhf_b    = (u16*)alloc((size_t)768 * 256 * 2);
  u16* Whhb_b    = (u16*)alloc((size_t)768 * 256 * 2);
  u16* We_b      = (u16*)alloc((size_t)256 * 512 * 2);
  u16* Wd_b      = (u16*)alloc((size_t)256 * 256 * 2);
  u16* Wproj_b   = (u16*)alloc((size_t)256 * 512 * 2);
  u16* Wg        = (u16*)alloc((size_t)1024 * 768 * 2);
  u16* Wfc_b     = (u16*)alloc((size_t)256 * 768 * 2);
  u16* cat0      = (u16*)alloc((size_t)BSZ * 768 * 2);
  u16* cat1      = (u16*)alloc((size_t)BSZ * 768 * 2);
  (void)alloc(65536);  // pad: attn8 A-fragments over-read past last rows

  float* hbuf[2] = {h0f, h1f};

  // tables + weight packs
  k_gi_table<<<dim3(64, 3), 256, 0, stream>>>(enc_emb, eWih_f, EDIM, ebih_f, tabf);
  k_gi_table<<<dim3(64, 3), 256, 0, stream>>>(enc_emb, eWih_b, EDIM, ebih_b, tabb);
  k_gi_table<<<dim3(256, 3), 256, 0, stream>>>(dec_emb, dWih, 640, dbih, tabd);
  k_gather<<<dim3(TLEN - 1, BSZ), 256, 0, stream>>>(tabd, trg, gi_t);
  k_pack<<<dim3(768), 256, 0, stream>>>(Whhf_b, eWhh_f, 256, 0, 256);
  k_pack<<<dim3(768), 256, 0, stream>>>(Whhb_b, eWhh_b, 256, 0, 256);
  k_pack<<<dim3(256), 256, 0, stream>>>(We_b, Wattn, 768, 256, 512);
  k_pack<<<dim3(256), 256, 0, stream>>>(Wd_b, Wattn, 768, 0, 256);
  k_pack<<<dim3(256), 256, 0, stream>>>(Wproj_b, Wproj, 512, 0, 512);
  k_pack_gates<<<dim3(1024), 256, 0, stream>>>(Wg, dWih, dWhh);
  k_pack<<<dim3(256), 256, 0, stream>>>(Wfc_b, Wfc, 768, 0, 768);

  // encoder v3: register-resident weights, 256 blocks = 128 rowgrps x 2 dirs
  {
    EncArgs ea{enc_b, hcatB, src, Whhf_b, Whhb_b, ebhh_f, ebhh_b, tabf, tabb};
    k_enc_p<<<dim3(256), dim3(1024), 0, stream>>>(ea);
  }

  // hdec = hcat @ Wproj^T + bproj (fp32 out), then bf16 into cat0[512:768]
  k_bgemm<false><<<dim3(8, 4), 256, 0, stream>>>(hcatB, 512, Wproj_b, 512, bproj, h0f, 256, 512);
  k_h2b<<<dim3(BSZ), 256, 0, stream>>>(h0f, cat0);

  // enc_pre (bf16) = enc_b @ We^T + battn
  k_bgemm<true><<<dim3(256, 4), 256, 0, stream>>>(enc_b, 512, We_b, 512, battn,
                                                  enc_pre_b, 256, 512);
  k_zero0<<<dim3(BSZ), 256, 0, stream>>>(dout);

  // decoder: 31 steps x 2 kernels (ep fused into next attn8) + final ep
  for (int t = 0; t < TLEN - 1; ++t) {
    u16* cc = (t & 1) ? cat1 : cat0;
    u16* bt = bcat + (size_t)t * BSZ * 768;
    const float* gip = (t > 0) ? (gi_t + (size_t)(t - 1) * BSZ * 768) : gi_t;
    u16* btp = (t > 0) ? (bcat + (size_t)(t - 1) * BSZ * 768) : bcat;
    k_attn8_ep<<<dim3(128), 256, 0, stream>>>(cc, enc_pre_b, enc_b, v_attn, Wd_b, bt,
                                              gbuf, gip, dbhh, hbuf[(t + 1) & 1],
                                              hbuf[t & 1], btp, (t > 0) ? 1 : 0);
    k_bgemm<false><<<dim3(8, 16), 256, 0, stream>>>(cc, 768, Wg, 768, nullptr, gbuf, 1024, 768);
  }
  // final epilogue for t=30: h(31) -> bcat[30][0:256]
  k_gru_ep<<<dim3(BSZ), 256, 0, stream>>>(gbuf, gi_t + (size_t)30 * BSZ * 768, dbhh,
                                          hbuf[0], hbuf[1], bcat + (size_t)30 * BSZ * 768);

  // deferred logits: [hn|ctx] @ Wfc^T + bfc for all 31 steps at once
  k_bgemm_logits<<<dim3(248, 4), 256, 0, stream>>>(bcat, Wfc_b, bfc, dout);
}